// Round 2
// baseline (2085.997 us; speedup 1.0000x reference)
//
#include <hip/hip_runtime.h>
#include <hip/hip_bf16.h>
#include <math.h>

#define B_ 8
#define L_ 512
#define DV_ 512
#define DM_ 512
#define PL_ 96
#define EL_ 3
#define DS_ 16
#define DC_ 4
#define DI_ 1024
#define DTR_ 32
#define S_ 512
#define CH_ 16         // scan chunks
#define CS_ 32         // steps per chunk

typedef float f32x4 __attribute__((ext_vector_type(4)));
typedef short bf16x8 __attribute__((ext_vector_type(8)));
typedef short bf16x4 __attribute__((ext_vector_type(4)));

__device__ __forceinline__ float bf2f(short s) {
  unsigned u = ((unsigned)(unsigned short)s) << 16;
  return __builtin_bit_cast(float, u);
}
__device__ __forceinline__ short f2bf(float f) {
  unsigned u = __builtin_bit_cast(unsigned, f);
  u = u + 0x7FFFu + ((u >> 16) & 1u);   // RNE
  return (short)(u >> 16);
}
__device__ __forceinline__ float h2f(unsigned short u) {
  _Float16 h = __builtin_bit_cast(_Float16, u);
  return (float)h;
}
__device__ __forceinline__ unsigned short f2h(float f) {
  _Float16 h = (_Float16)f;
  return __builtin_bit_cast(unsigned short, h);
}

// lgkm-only barrier (no vmcnt drain): global prefetch stays in flight.
__device__ __forceinline__ void lds_barrier() {
  __builtin_amdgcn_sched_barrier(0);
  __builtin_amdgcn_s_waitcnt(0xC07F);
  __builtin_amdgcn_s_barrier();
  __builtin_amdgcn_sched_barrier(0);
}

// ---------------------------------------------------------------------------
// One-shot fp32 -> bf16 conversion of ALL GEMM weights into workspace.
// Segment bounds in float4 units (compile-time).
// ---------------------------------------------------------------------------
#define WC0 65536                 // emb_w      512*512
#define WC1 (WC0 + 1572864)       // m_in_w     6*2048*512
#define WC2 (WC1 + 98304)         // m_xp_w     6*64*1024
#define WC3 (WC2 + 49152)         // m_dt_w     6*1024*32
#define WC4 (WC3 + 786432)        // m_out_w    6*512*1024
#define WC5 (WC4 + 786432)        // ffn_w1     3*2048*512
#define WC6 (WC5 + 786432)        // ffn_w2     3*512*2048
#define WC7 (WC6 + 12288)        // proj_w     96*512
// WC7 = 4157440 float4s; grid = 16240 * 256 exactly.

__global__ __launch_bounds__(256)
void wcvt_k(const float* __restrict__ e, const float* __restrict__ iw,
            const float* __restrict__ xp, const float* __restrict__ dtw,
            const float* __restrict__ ow, const float* __restrict__ w1,
            const float* __restrict__ w2, const float* __restrict__ pw,
            short* __restrict__ de, short* __restrict__ di,
            short* __restrict__ dxp, short* __restrict__ ddt,
            short* __restrict__ dow, short* __restrict__ dw1,
            short* __restrict__ dw2, short* __restrict__ dpw)
{
  int idx = blockIdx.x * 256 + threadIdx.x;
  const float* s; short* d; int off;
  if (idx < WC0)      { s = e;   d = de;  off = idx; }
  else if (idx < WC1) { s = iw;  d = di;  off = idx - WC0; }
  else if (idx < WC2) { s = xp;  d = dxp; off = idx - WC1; }
  else if (idx < WC3) { s = dtw; d = ddt; off = idx - WC2; }
  else if (idx < WC4) { s = ow;  d = dow; off = idx - WC3; }
  else if (idx < WC5) { s = w1;  d = dw1; off = idx - WC4; }
  else if (idx < WC6) { s = w2;  d = dw2; off = idx - WC5; }
  else                { s = pw;  d = dpw; off = idx - WC6; }
  float4 v = ((const float4*)s)[off];
  union { short sh[4]; int2 p; } r;
  r.sh[0] = f2bf(v.x); r.sh[1] = f2bf(v.y);
  r.sh[2] = f2bf(v.z); r.sh[3] = f2bf(v.w);
  ((int2*)d)[off] = r.p;
}

// ---------------------------------------------------------------------------
// Instance-norm statistics over the time axis (L) of x (B,L,DV) fp32.
// ---------------------------------------------------------------------------
__global__ __launch_bounds__(256)
void stats_k(const float* __restrict__ x, float* __restrict__ means,
             float* __restrict__ stdev, float* __restrict__ rstd,
             float* __restrict__ xlast)
{
  int d = blockIdx.x * 256 + threadIdx.x;       // 0..511
  int b = blockIdx.y;
  const float* xp = x + (size_t)b * L_ * DV_ + d;
  float s = 0.f, ss = 0.f;
  for (int l = 0; l < L_; l++) {
    float v = xp[(size_t)l * DV_];
    s += v; ss += v * v;
  }
  float mu = s / (float)L_;
  float var = ss / (float)L_ - mu * mu;
  float sd = sqrtf(var + 1e-5f);
  float rs = 1.f / sd;
  int idx = b * DV_ + d;
  means[idx] = mu; stdev[idx] = sd; rstd[idx] = rs;
  xlast[idx] = (xp[(size_t)(L_ - 1) * DV_] - mu) * rs;
}

// ---------------------------------------------------------------------------
// Normalize + transpose: xnT[b,d,l] = (x[b,l,d]-mu[b,d])*rstd[b,d]  (bf16)
// ---------------------------------------------------------------------------
__global__ __launch_bounds__(256)
void tnorm_k(const float* __restrict__ x, const float* __restrict__ means,
             const float* __restrict__ rstd, short* __restrict__ xnT)
{
  __shared__ float tile[64][65];
  const int t = threadIdx.x;
  const int j = t & 63;
  const int i0 = t >> 6;                 // 0..3
  const int bz = blockIdx.z;
  const int l0 = blockIdx.y << 6;
  const int d0 = blockIdx.x << 6;
  const float* xp = x + ((size_t)bz * L_ + l0) * DV_ + d0;
  #pragma unroll
  for (int i = i0; i < 64; i += 4) tile[i][j] = xp[(size_t)i * DV_ + j];
  __syncthreads();
  short* op = xnT + ((size_t)bz * DV_ + d0) * L_ + l0;
  const int sb = bz * DV_ + d0;
  #pragma unroll
  for (int i = i0; i < 64; i += 4) {
    float mu = means[sb + i];
    float rs = rstd[sb + i];
    op[(size_t)i * L_ + j] = f2bf((tile[j][i] - mu) * rs);
  }
}

// ---------------------------------------------------------------------------
// Fused LayerNorm: optionally h += add (+ abias) in place, then LN -> bf16.
// ADD: 0 = plain, 1 = h += bf16 add, 2 = h += bf16 add + fp32 bias[col].
// ---------------------------------------------------------------------------
template <int ADD>
__global__ __launch_bounds__(256)
void ln_k(float* __restrict__ X, const short* __restrict__ add,
          const float* __restrict__ abias,
          const float* __restrict__ g, const float* __restrict__ b,
          short* __restrict__ Y)
{
  int row = blockIdx.x;
  float* x = X + (size_t)row * DM_;
  int t = threadIdx.x;
  float v0 = x[t], v1 = x[t + 256];
  if constexpr (ADD >= 1) {
    v0 += bf2f(add[(size_t)row * DM_ + t]);
    v1 += bf2f(add[(size_t)row * DM_ + t + 256]);
    if constexpr (ADD == 2) { v0 += abias[t]; v1 += abias[t + 256]; }
    x[t] = v0; x[t + 256] = v1;
  }
  float s = v0 + v1, ss = v0 * v0 + v1 * v1;
  #pragma unroll
  for (int o = 1; o < 64; o <<= 1) { s += __shfl_xor(s, o); ss += __shfl_xor(ss, o); }
  __shared__ float sb[8];
  int wave = t >> 6, lane = t & 63;
  if (lane == 0) { sb[wave] = s; sb[4 + wave] = ss; }
  __syncthreads();
  s = sb[0] + sb[1] + sb[2] + sb[3];
  ss = sb[4] + sb[5] + sb[6] + sb[7];
  float mu = s / (float)DM_;
  float var = ss / (float)DM_ - mu * mu;
  float rs = rsqrtf(var + 1e-5f);
  Y[(size_t)row * DM_ + t]       = f2bf((v0 - mu) * rs * g[t]       + b[t]);
  Y[(size_t)row * DM_ + t + 256] = f2bf((v1 - mu) * rs * g[t + 256] + b[t + 256]);
}

// ---------------------------------------------------------------------------
// Depthwise causal conv (DC=4 taps) + bias + silu.  REV templated.
// ---------------------------------------------------------------------------
template <int REV>
__global__ __launch_bounds__(256)
void conv_k(const short* __restrict__ xz, const float* __restrict__ w,
            const float* __restrict__ cb, short* __restrict__ xc)
{
  int idx = blockIdx.x * 256 + threadIdx.x;   // over B*S*DI
  int i = idx & (DI_ - 1);
  int bs = idx >> 10;                         // b*S + t
  int tt0 = bs & (S_ - 1);
  int b = bs >> 9;
  const short* u = xz + (size_t)b * S_ * (2 * DI_) + i;   // row stride 2*DI
  float acc = cb[i];
  #pragma unroll
  for (int k = 0; k < DC_; k++) {
    int tt = REV ? (tt0 + (DC_ - 1) - k) : (tt0 - (DC_ - 1) + k);
    if (tt >= 0 && tt < S_)
      acc += w[i * DC_ + k] * bf2f(u[(size_t)tt * (2 * DI_)]);
  }
  float sig = 1.f / (1.f + __expf(-acc));
  xc[idx] = f2bf(acc * sig);
}

// ---------------------------------------------------------------------------
// Chunked selective scan: state dim split 4-ways across adjacent lanes
// (thread (b,i,q) owns states n=4q..4q+3); grid 2048 blocks for occupancy.
// ---------------------------------------------------------------------------
template <int REV>
__global__ __launch_bounds__(256)
void scan_p1(const unsigned short* __restrict__ dt16, const short* __restrict__ xc,
             const short* __restrict__ xdbl, const float* __restrict__ A_log,
             unsigned short* __restrict__ part_h, unsigned short* __restrict__ part_A)
{
  const int gid = blockIdx.x * 256 + threadIdx.x;   // over B*DI*4
  const int q = gid & 3;                            // state quad
  const int i = (gid >> 2) & (DI_ - 1);
  const int b = gid >> 12;
  const int c = blockIdx.y;
  float Ai[4];
  const float* al = A_log + i * DS_ + q * 4;
  #pragma unroll
  for (int n = 0; n < 4; n++) Ai[n] = -__expf(al[n]);

  const int ti0 = REV ? (S_ - 1 - c * CS_) : (c * CS_);
  const unsigned short* pdt = dt16 + ((size_t)b * S_ + ti0) * DI_ + i;
  const short* pu = xc + ((size_t)b * S_ + ti0) * DI_ + i;
  const short* pbc = xdbl + (((size_t)b * S_ + ti0) << 6) + DTR_ + q * 4;
  const int sstep = REV ? -DI_ : DI_;
  const int sbc = REV ? -64 : 64;

  float h[4];
  #pragma unroll
  for (int n = 0; n < 4; n++) h[n] = 0.f;
  float dsum = 0.f;

  #pragma unroll 4
  for (int sl = 0; sl < CS_; sl++) {
    float dtv = h2f(*pdt);
    float u = bf2f(*pu);
    bf16x4 vB = *(const bf16x4*)pbc;
    float du = dtv * u;
    dsum += dtv;
    #pragma unroll
    for (int n = 0; n < 4; n++) {
      float dA = __expf(dtv * Ai[n]);
      h[n] = dA * h[n] + du * bf2f(vB[n]);
    }
    pdt += sstep; pu += sstep; pbc += sbc;
  }
  union { unsigned short s[4]; int2 v; } uh, ua;
  #pragma unroll
  for (int n = 0; n < 4; n++) {
    uh.s[n] = f2h(h[n]);
    ua.s[n] = f2h(__expf(Ai[n] * dsum));   // exact: prod exp(dt*A)=exp(A*sum dt)
  }
  const size_t ix = ((((size_t)c * B_ + b) * DI_ + i) << 4) + (q << 2);
  *(int2*)(part_h + ix) = uh.v;
  *(int2*)(part_A + ix) = ua.v;
}

__global__ __launch_bounds__(256)
void scan_p2(unsigned short* __restrict__ part_h,
             const unsigned short* __restrict__ part_A)
{
  const size_t gid = (size_t)blockIdx.x * 256 + threadIdx.x;   // B*DI*DS
  const size_t stride = (size_t)B_ * DI_ * DS_;
  float hin = 0.f;
  #pragma unroll
  for (int c = 0; c < CH_; c++) {
    size_t ix = (size_t)c * stride + gid;
    float hh = h2f(part_h[ix]);
    float pA = h2f(part_A[ix]);
    part_h[ix] = f2h(hin);            // becomes chunk c's incoming state
    hin = hh + pA * hin;
  }
}

// y may alias dt16 (element-exact same indices) — no __restrict__ on those.
template <int REV>
__global__ __launch_bounds__(256)
void scan_p3(const unsigned short* dt16, const short* __restrict__ xc,
             const short* __restrict__ xdbl, const short* __restrict__ xz,
             const float* __restrict__ A_log, const float* __restrict__ Dp,
             const unsigned short* __restrict__ part_h, short* y)
{
  const int gid = blockIdx.x * 256 + threadIdx.x;   // over B*DI*4
  const int q = gid & 3;                            // state quad
  const int i = (gid >> 2) & (DI_ - 1);
  const int b = gid >> 12;
  const int c = blockIdx.y;
  float Ai[4];
  const float* al = A_log + i * DS_ + q * 4;
  #pragma unroll
  for (int n = 0; n < 4; n++) Ai[n] = -__expf(al[n]);
  const float Di = Dp[i];

  float h[4];
  {
    const size_t ix = ((((size_t)c * B_ + b) * DI_ + i) << 4) + (q << 2);
    union { unsigned short s[4]; int2 v; } uh;
    uh.v = *(const int2*)(part_h + ix);
    #pragma unroll
    for (int n = 0; n < 4; n++) h[n] = h2f(uh.s[n]);
  }

  const int ti0 = REV ? (S_ - 1 - c * CS_) : (c * CS_);
  const unsigned short* pdt = dt16 + ((size_t)b * S_ + ti0) * DI_ + i;
  const short* pu = xc + ((size_t)b * S_ + ti0) * DI_ + i;
  const short* pbc = xdbl + (((size_t)b * S_ + ti0) << 6) + DTR_ + q * 4;
  const short* pz = xz + ((size_t)b * S_ + ti0) * (2 * DI_) + DI_ + i;
  short* py = y + ((size_t)b * S_ + ti0) * DI_ + i;
  const int sstep = REV ? -DI_ : DI_;
  const int sbc = REV ? -64 : 64;
  const int sz = REV ? -(2 * DI_) : (2 * DI_);

  #pragma unroll 4
  for (int sl = 0; sl < CS_; sl++) {
    float dtv = h2f(*pdt);
    float u = bf2f(*pu);
    bf16x4 vB = *(const bf16x4*)pbc;
    bf16x4 vC = *(const bf16x4*)(pbc + DS_);
    float zv = bf2f(*pz);
    float du = dtv * u;
    float yp = 0.f;
    #pragma unroll
    for (int n = 0; n < 4; n++) {
      float dA = __expf(dtv * Ai[n]);
      h[n] = dA * h[n] + du * bf2f(vB[n]);
      yp += h[n] * bf2f(vC[n]);
    }
    yp += __shfl_xor(yp, 1);
    yp += __shfl_xor(yp, 2);            // quad-wide sum over all 16 states
    float sil = zv / (1.f + __expf(-zv));
    float yv = (yp + u * Di) * sil;
    if (q == 0) *py = f2bf(yv);
    pdt += sstep; pu += sstep; pbc += sbc; pz += sz; py += sstep;
  }
}

// ---------------------------------------------------------------------------
// bf16 MFMA GEMM: C[M,N] = A[M,K] * W[N,K]^T, fp32 accum.  A and W both bf16
// (weights pre-converted once by wcvt_k).  Split-source concat-K.  Double-
// buffered LDS, lgkm-only barrier, XOR swizzle, 2x2 waves.  Register
// prefetch holds TWO slabs in flight (loads for slab kb+3 issued at kb) to
// cover L2/HBM latency at low block-per-CU counts.
// ---------------------------------------------------------------------------
enum { EPI_F32_BIAS, EPI_BF16, EPI_F16_SOFTPLUS, EPI_HALF_BF16, EPI_GELU,
       EPI_PROJ };

template <int EPI, int BM, int BN, int BK>
__global__ __launch_bounds__(256)
void gemm_k(const short* __restrict__ A0, const short* __restrict__ A1,
            const short* __restrict__ W0, const short* __restrict__ W1,
            int khalf, int N, int K, int lda, int ldw,
            float* __restrict__ Cf, short* __restrict__ Cb, int ldc,
            const float* __restrict__ bias,
            const float* __restrict__ xlast, const float* __restrict__ stdev,
            const float* __restrict__ means)
{
  constexpr int MT = BM / 32;           // 16-row m-tiles per wave
  constexpr int NT = BN / 32;
  constexpr int KS = BK / 32;
  constexpr int CHK = BK / 8;           // 16B chunks per row
  constexpr int MSK = CHK - 1;
  constexpr int NA = (BM * CHK) / 256;
  constexpr int NW = (BN * CHK) / 256;
  __shared__ __align__(16) short As[2][BM * BK];
  __shared__ __align__(16) short Ws[2][BN * BK];
  const int tid = threadIdx.x;
  const int m0 = blockIdx.x * BM;       // fastest dim = m (XCD locality of A)
  const int n0 = blockIdx.y * BN;
  const int wave = tid >> 6, lane = tid & 63;
  const int wm = (wave & 1) * (BM / 2), wn = (wave >> 1) * (BN / 2);
  const int quad = lane >> 4, l16 = lane & 15;

  f32x4 acc[MT][NT] = {};

  size_t aoff[NA]; int apos[NA];
  #pragma unroll
  for (int j = 0; j < NA; j++) {
    int id = tid + j * 256;
    int r = id / CHK, q = id % CHK;
    aoff[j] = (size_t)(m0 + r) * lda + q * 8;
    apos[j] = r * BK + ((q ^ (r & MSK)) << 3);
  }
  size_t woff[NW]; int wpos[NW];
  #pragma unroll
  for (int j = 0; j < NW; j++) {
    int id = tid + j * 256;
    int r = id / CHK, q = id % CHK;
    int wr = n0 + r; if (wr > N - 1) wr = N - 1;
    woff[j] = (size_t)wr * ldw + q * 8;
    wpos[j] = r * BK + ((q ^ (r & MSK)) << 3);
  }

  const int KB = K / BK;
  int4 ar[2][NA], wvr[2][NW];

  // prologue: slab 0 -> LDS[0] direct; issue slab 1 and slab 2 loads.
  #pragma unroll
  for (int j = 0; j < NA; j++) ar[0][j] = *(const int4*)(A0 + aoff[j]);
  #pragma unroll
  for (int j = 0; j < NW; j++) wvr[0][j] = *(const int4*)(W0 + woff[j]);
  #pragma unroll
  for (int j = 0; j < NA; j++) *(int4*)(&As[0][0] + apos[j]) = ar[0][j];
  #pragma unroll
  for (int j = 0; j < NW; j++) *(int4*)(&Ws[0][0] + wpos[j]) = wvr[0][j];
  if (KB > 1) {
    const short* Ab = (BK < khalf) ? A0 + BK : A1 + (BK - khalf);
    const short* Wb = (BK < khalf) ? W0 + BK : W1 + (BK - khalf);
    #pragma unroll
    for (int j = 0; j < NA; j++) ar[0][j] = *(const int4*)(Ab + aoff[j]);
    #pragma unroll
    for (int j = 0; j < NW; j++) wvr[0][j] = *(const int4*)(Wb + woff[j]);
  }
  if (KB > 2) {
    const int k0 = 2 * BK;
    const short* Ab = (k0 < khalf) ? A0 + k0 : A1 + (k0 - khalf);
    const short* Wb = (k0 < khalf) ? W0 + k0 : W1 + (k0 - khalf);
    #pragma unroll
    for (int j = 0; j < NA; j++) ar[1][j] = *(const int4*)(Ab + aoff[j]);
    #pragma unroll
    for (int j = 0; j < NW; j++) wvr[1][j] = *(const int4*)(Wb + woff[j]);
  }
  lds_barrier();

  for (int kb = 0; kb < KB; kb++) {
    const int cur = kb & 1;
    bf16x8 af[MT][KS], bfr[NT][KS];
    #pragma unroll
    for (int mt = 0; mt < MT; mt++)
      #pragma unroll
      for (int st = 0; st < KS; st++)
        af[mt][st] = *(const bf16x8*)(&As[cur][0] + (wm + mt * 16 + l16) * BK +
                                      (((st * 4 + quad) ^ (l16 & MSK)) << 3));
    #pragma unroll
    for (int nt = 0; nt < NT; nt++)
      #pragma unroll
      for (int st = 0; st < KS; st++)
        bfr[nt][st] = *(const bf16x8*)(&Ws[cur][0] + (wn + nt * 16 + l16) * BK +
                                       (((st * 4 + quad) ^ (l16 & MSK)) << 3));
    if (kb + 1 < KB) {
      // stage slab kb+1 (in regs for 2 iters) into the other LDS buffer,
      // then refill the same reg set with slab kb+3.
      #pragma unroll
      for (int j = 0; j < NA; j++) *(int4*)(&As[cur ^ 1][0] + apos[j]) = ar[cur][j];
      #pragma unroll
      for (int j = 0; j < NW; j++) *(int4*)(&Ws[cur ^ 1][0] + wpos[j]) = wvr[cur][j];
      if (kb + 3 < KB) {
        const int k0 = (kb + 3) * BK;
        const short* Ab = (k0 < khalf) ? A0 + k0 : A1 + (k0 - khalf);
        const short* Wb = (k0 < khalf) ? W0 + k0 : W1 + (k0 - khalf);
        #pragma unroll
        for (int j = 0; j < NA; j++) ar[cur][j] = *(const int4*)(Ab + aoff[j]);
        #pragma unroll
        for (int j = 0; j < NW; j++) wvr[cur][j] = *(const int4*)(Wb + woff[j]);
      }
    }
    #pragma unroll
    for (int st = 0; st < KS; st++)
      #pragma unroll
      for (int mt = 0; mt < MT; mt++)
        #pragma unroll
        for (int nt = 0; nt < NT; nt++)
          acc[mt][nt] = __builtin_amdgcn_mfma_f32_16x16x32_bf16(
              af[mt][st], bfr[nt][st], acc[mt][nt], 0, 0, 0);
    lds_barrier();
  }

  #pragma unroll
  for (int mt = 0; mt < MT; mt++) {
    #pragma unroll
    for (int nt = 0; nt < NT; nt++) {
      int n = n0 + wn + nt * 16 + l16;
      if (n >= N) continue;
      #pragma unroll
      for (int r = 0; r < 4; r++) {
        int m = m0 + wm + mt * 16 + quad * 4 + r;
        float v = acc[mt][nt][r];
        if constexpr (EPI == EPI_F32_BIAS) {
          Cf[(size_t)m * ldc + n] = v + bias[n];
        } else if constexpr (EPI == EPI_BF16) {
          Cb[(size_t)m * ldc + n] = f2bf(v);
        } else if constexpr (EPI == EPI_F16_SOFTPLUS) {
          float tt = v + bias[n];
          float sp = (tt > 20.f) ? tt : log1pf(__expf(tt));
          ((unsigned short*)Cb)[(size_t)m * ldc + n] = f2h(sp);
        } else if constexpr (EPI == EPI_HALF_BF16) {
          Cb[(size_t)m * ldc + n] = f2bf(0.5f * v);
        } else if constexpr (EPI == EPI_GELU) {
          float tt = v + bias[n];
          Cb[(size_t)m * ldc + n] = f2bf(0.5f * tt * (1.f + erff(tt * 0.70710678118f)));
        } else if constexpr (EPI == EPI_PROJ) {
          int bb = m >> 9, d = m & 511;
          float tt = v + bias[n] + xlast[m];
          tt = tt * stdev[m] + means[m];
          Cf[((size_t)bb * PL_ + n) * DV_ + d] = tt;
        }
      }
    }
  }
}

// ---------------------------------------------------------------------------
extern "C" void kernel_launch(void* const* d_in, const int* in_sizes, int n_in,
                              void* d_out, int out_size, void* d_ws, size_t ws_size,
                              hipStream_t stream)
{
  (void)in_sizes; (void)n_in; (void)out_size; (void)ws_size;
  const float* x        = (const float*)d_in[0];
  const float* emb_w    = (const float*)d_in[1];
  const float* emb_b    = (const float*)d_in[2];
  const float* ln_g     = (const float*)d_in[3];
  const float* ln_b     = (const float*)d_in[4];
  const float* m_in_w   = (const float*)d_in[5];
  const float* m_conv_w = (const float*)d_in[6];
  const float* m_conv_b = (const float*)d_in[7];
  const float* m_xp_w   = (const float*)d_in[8];
  const float* m_dt_w   = (const float*)d_in[9];
  const float* m_dt_b   = (const float*)d_in[10];
  const float* m_A_log  = (const float*)d_in[11];
  const float* m_D      = (const float*)d_in[12];
  const float* m_out_w  = (const float*)d_in[13];
  const float* ffn_ln_g = (const float*)d_in[14];
  const float* ffn_ln_b = (const float*)d_in[15];
  const float* ffn_w1   = (const float*)d_in[16];
  const float* ffn_b1   = (const float*)d_in[17];
  const float* ffn_w2   = (const float*)d_in[18];
  const float* ffn_b2   = (const float*)d_in[19];
  const float* enc_g    = (const float*)d_in[20];
  const float* enc_b    = (const float*)d_in[21];
  const float* proj_w   = (const float*)d_in[22];
  const float* proj_b   = (const float*)d_in[23];
  float* out = (float*)d_out;

  char* ws = (char*)d_ws;
  const size_t MB = 1024 * 1024;
  float* h      = (float*)(ws + 0);        //  8 MB fp32 residual stream
  short* hn     = (short*)(ws + 8 * MB);   //  4 MB LN output bf16
  short* xz     = (short*)(ws + 12 * MB);  // 16 MB [M][2048] per-dir
  short* xc     = (short*)(ws + 28 * MB);  //  8 MB [M][1024] per-dir
  short* xdbl   = (short*)(ws + 36 * MB);  // .5 MB [M][64]
  float* stats  = (float*)(ws + 36 * MB + 512 * 1024);          // 64 KB
  unsigned short* dtb = (unsigned short*)(ws + 37 * MB); // 8 MB fp16 dt; scan_p3 dir1 writes y in place
  unsigned short* part_h = (unsigned short*)(ws + 45 * MB);     // 4 MB (scan only)
  unsigned short* part_A = (unsigned short*)(ws + 49 * MB);     // 4 MB (scan only)
  short* vtmp   = (short*)(ws + 47 * MB);  // 4 MB bf16 mamba out (after scans done)
  short* ftmp   = (short*)(ws + 47 * MB);  // 4 MB bf16 ffn2 out (aliases vtmp, sequential)
  short* yact0  = (short*)(ws + 53 * MB);  //  8 MB y(dir0); xnT aliases pre-layer
  short* xnT    = (short*)(ws + 53 * MB);
  float* means = stats, *stdevp = stats + 4096, *rstd = stats + 8192, *xlast = stats + 12288;

  // bf16 weight pool @ 61 MB (~32 MB total, high-water ~93 MB)
  short* emb_wb = (short*)(ws + 61 * MB);
  short* in_wb  = emb_wb + 262144;      // 6 x 2048x512
  short* xp_wb  = in_wb  + 6291456;     // 6 x 64x1024
  short* dt_wb  = xp_wb  + 393216;      // 6 x 1024x32
  short* out_wb = dt_wb  + 196608;      // 6 x 512x1024
  short* w1b    = out_wb + 3145728;     // 3 x 2048x512
  short* w2b    = w1b    + 3145728;     // 3 x 512x2048
  short* projb  = w2b    + 3145728;     // 96x512

  dim3 blk(256);
  const int NOSPLIT = 1 << 30;

  wcvt_k<<<dim3(16240), blk, 0, stream>>>(
      emb_w, m_in_w, m_xp_w, m_dt_w, m_out_w, ffn_w1, ffn_w2, proj_w,
      emb_wb, in_wb, xp_wb, dt_wb, out_wb, w1b, w2b, projb);

  stats_k<<<dim3(2, B_), blk, 0, stream>>>(x, means, stdevp, rstd, xlast);
  tnorm_k<<<dim3(8, 8, B_), blk, 0, stream>>>(x, means, rstd, xnT);
  // emb: M=4096, N=512, K=512 — 64x32 BK=64, grid (64, 16)
  gemm_k<EPI_F32_BIAS, 64, 32, 64><<<dim3(64, 16), blk, 0, stream>>>(
      xnT, xnT, emb_wb, emb_wb, NOSPLIT, DM_, L_, L_, L_,
      h, nullptr, DM_, emb_b, nullptr, nullptr, nullptr);

  for (int il = 0; il < EL_; il++) {
    if (il == 0)
      ln_k<0><<<dim3(4096), blk, 0, stream>>>(h, nullptr, nullptr, ln_g, ln_b, hn);
    else
      ln_k<2><<<dim3(4096), blk, 0, stream>>>(h, ftmp, ffn_b2 + (il - 1) * DM_,
          ln_g + il * DM_, ln_b + il * DM_, hn);
    for (int dir = 0; dir < 2; dir++) {
      int mod = 2 * il + dir;
      // in-proj: N=2048, K=512 — 64x128 BK=32, grid (64, 16) = 1024 blocks
      gemm_k<EPI_BF16, 64, 128, 32><<<dim3(64, 16), blk, 0, stream>>>(
          hn, hn, in_wb + (size_t)mod * 2 * DI_ * DM_,
          in_wb + (size_t)mod * 2 * DI_ * DM_, NOSPLIT, 2 * DI_, DM_, DM_, DM_,
          nullptr, xz, 2 * DI_, nullptr, nullptr, nullptr, nullptr);
      if (dir == 0)
        conv_k<0><<<dim3(16384), blk, 0, stream>>>(
            xz, m_conv_w + (size_t)mod * DI_ * DC_, m_conv_b + (size_t)mod * DI_, xc);
      else
        conv_k<1><<<dim3(16384), blk, 0, stream>>>(
            xz, m_conv_w + (size_t)mod * DI_ * DC_, m_conv_b + (size_t)mod * DI_, xc);
      // xdbl: N=64, K=1024 — 32x32 BK=64, grid (128, 2)
      gemm_k<EPI_BF16, 32, 32, 64><<<dim3(128, 2), blk, 0, stream>>>(
          xc, xc, xp_wb + (size_t)mod * (DTR_ + 2 * DS_) * DI_,
          xp_wb + (size_t)mod * (DTR_ + 2 * DS_) * DI_, NOSPLIT,
          DTR_ + 2 * DS_, DI_, DI_, DI_,
          nullptr, xdbl, DTR_ + 2 * DS_, nullptr, nullptr, nullptr, nullptr);
      // dt: N=1024, K=32 — 64x64 BK=32, grid (64, 16)
      gemm_k<EPI_F16_SOFTPLUS, 64, 64, 32><<<dim3(64, 16), blk, 0, stream>>>(
          xdbl, xdbl, dt_wb + (size_t)mod * DI_ * DTR_,
          dt_wb + (size_t)mod * DI_ * DTR_, NOSPLIT, DI_, DTR_, DTR_ + 2 * DS_, DTR_,
          nullptr, (short*)dtb, DI_, m_dt_b + (size_t)mod * DI_, nullptr, nullptr, nullptr);
      const float* Alog = m_A_log + (size_t)mod * DI_ * DS_;
      const float* Dp = m_D + (size_t)mod * DI_;
      short* ydst = (dir == 0) ? yact0 : (short*)dtb;   // dir1: in-place over dtb
      if (dir == 0) {
        scan_p1<0><<<dim3(128, CH_), blk, 0, stream>>>(dtb, xc, xdbl, Alog, part_h, part_A);
        scan_p2<<<dim3(512), blk, 0, stream>>>(part_h, part_A);
        scan_p3<0><<<dim3(128, CH_), blk, 0, stream>>>(dtb, xc, xdbl, xz, Alog, Dp, part_h, ydst);
      } else {
        scan_p1<1><<<dim3(128, CH_), blk, 0, stream>>>(dtb, xc, xdbl, Alog, part_h, part_A);
        scan_p2<<<dim3(512), blk, 0, stream>>>(part_h, part_A);
        scan_p3<1><<<dim3(128, CH_), blk, 0, stream>>>(dtb, xc, xdbl, xz, Alog, Dp, part_h, ydst);
      }
    }
    // out-proj (concat-K): vtmp = 0.5*(yf.Wf^T + yb.Wb^T) — 64x32 BK=64, grid (64,16)
    gemm_k<EPI_HALF_BF16, 64, 32, 64><<<dim3(64, 16), blk, 0, stream>>>(
        yact0, (const short*)dtb,
        out_wb + (size_t)(2 * il) * DM_ * DI_,
        out_wb + (size_t)(2 * il + 1) * DM_ * DI_,
        DI_, DM_, 2 * DI_, DI_, DI_,
        nullptr, vtmp, DM_, nullptr, nullptr, nullptr, nullptr);
    // fused: h += vtmp, then LN
    ln_k<1><<<dim3(4096), blk, 0, stream>>>(h, vtmp, nullptr,
        ffn_ln_g + il * DM_, ffn_ln_b + il * DM_, hn);
    // ffn1: N=2048, K=512 — 64x128 BK=32, grid (64, 16)
    gemm_k<EPI_GELU, 64, 128, 32><<<dim3(64, 16), blk, 0, stream>>>(
        hn, hn, w1b + (size_t)il * 4 * DM_ * DM_,
        w1b + (size_t)il * 4 * DM_ * DM_, NOSPLIT, 4 * DM_, DM_, DM_, DM_,
        nullptr, xz, 4 * DM_, ffn_b1 + (size_t)il * 4 * DM_, nullptr, nullptr, nullptr);
    // ffn2: N=512, K=2048 — 64x32 BK=64, grid (64, 16); streaming bf16 out
    gemm_k<EPI_BF16, 64, 32, 64><<<dim3(64, 16), blk, 0, stream>>>(
        xz, xz, w2b + (size_t)il * DM_ * 4 * DM_,
        w2b + (size_t)il * DM_ * 4 * DM_, NOSPLIT, DM_, 4 * DM_, 4 * DM_, 4 * DM_,
        nullptr, ftmp, DM_, nullptr, nullptr, nullptr, nullptr);
    // h += ftmp + ffn_b2 happens in the next layer's LN (or enc-LN below)
  }

  ln_k<2><<<dim3(4096), blk, 0, stream>>>(h, ftmp, ffn_b2 + 2 * DM_,
      enc_g, enc_b, hn);
  // proj: N=96, K=512 — 64x32 BK=64, grid (64, 3)
  gemm_k<EPI_PROJ, 64, 32, 64><<<dim3(64, 3), blk, 0, stream>>>(
      hn, hn, projb, projb, NOSPLIT, PL_, DM_, DM_, DM_,
      out, nullptr, 0, proj_b, xlast, stdevp, means);
}

// Round 3
// 1739.709 us; speedup vs baseline: 1.1990x; 1.1990x over previous
//
#include <hip/hip_runtime.h>
#include <hip/hip_bf16.h>
#include <math.h>

#define B_ 8
#define L_ 512
#define DV_ 512
#define DM_ 512
#define PL_ 96
#define EL_ 3
#define DS_ 16
#define DC_ 4
#define DI_ 1024
#define DTR_ 32
#define S_ 512
#define CH_ 16         // scan chunks
#define CS_ 32         // steps per chunk

typedef float f32x4 __attribute__((ext_vector_type(4)));
typedef short bf16x8 __attribute__((ext_vector_type(8)));
typedef short bf16x4 __attribute__((ext_vector_type(4)));

__device__ __forceinline__ float bf2f(short s) {
  unsigned u = ((unsigned)(unsigned short)s) << 16;
  return __builtin_bit_cast(float, u);
}
__device__ __forceinline__ short f2bf(float f) {
  unsigned u = __builtin_bit_cast(unsigned, f);
  u = u + 0x7FFFu + ((u >> 16) & 1u);   // RNE
  return (short)(u >> 16);
}
__device__ __forceinline__ float h2f(unsigned short u) {
  _Float16 h = __builtin_bit_cast(_Float16, u);
  return (float)h;
}
__device__ __forceinline__ unsigned short f2h(float f) {
  _Float16 h = (_Float16)f;
  return __builtin_bit_cast(unsigned short, h);
}

// lgkm-only barrier (no vmcnt drain): global prefetch stays in flight.
__device__ __forceinline__ void lds_barrier() {
  __builtin_amdgcn_sched_barrier(0);
  __builtin_amdgcn_s_waitcnt(0xC07F);
  __builtin_amdgcn_s_barrier();
  __builtin_amdgcn_sched_barrier(0);
}

// ---------------------------------------------------------------------------
// One-shot fp32 -> bf16 conversion of ALL GEMM weights into workspace.
// Segment bounds in float4 units (compile-time).
// ---------------------------------------------------------------------------
#define WC0 65536                 // emb_w      512*512
#define WC1 (WC0 + 1572864)       // m_in_w     6*2048*512
#define WC2 (WC1 + 98304)         // m_xp_w     6*64*1024
#define WC3 (WC2 + 49152)         // m_dt_w     6*1024*32
#define WC4 (WC3 + 786432)        // m_out_w    6*512*1024
#define WC5 (WC4 + 786432)        // ffn_w1     3*2048*512
#define WC6 (WC5 + 786432)        // ffn_w2     3*512*2048
#define WC7 (WC6 + 12288)        // proj_w     96*512
// WC7 = 4157440 float4s; grid = 16240 * 256 exactly.

__global__ __launch_bounds__(256)
void wcvt_k(const float* __restrict__ e, const float* __restrict__ iw,
            const float* __restrict__ xp, const float* __restrict__ dtw,
            const float* __restrict__ ow, const float* __restrict__ w1,
            const float* __restrict__ w2, const float* __restrict__ pw,
            short* __restrict__ de, short* __restrict__ di,
            short* __restrict__ dxp, short* __restrict__ ddt,
            short* __restrict__ dow, short* __restrict__ dw1,
            short* __restrict__ dw2, short* __restrict__ dpw)
{
  int idx = blockIdx.x * 256 + threadIdx.x;
  const float* s; short* d; int off;
  if (idx < WC0)      { s = e;   d = de;  off = idx; }
  else if (idx < WC1) { s = iw;  d = di;  off = idx - WC0; }
  else if (idx < WC2) { s = xp;  d = dxp; off = idx - WC1; }
  else if (idx < WC3) { s = dtw; d = ddt; off = idx - WC2; }
  else if (idx < WC4) { s = ow;  d = dow; off = idx - WC3; }
  else if (idx < WC5) { s = w1;  d = dw1; off = idx - WC4; }
  else if (idx < WC6) { s = w2;  d = dw2; off = idx - WC5; }
  else                { s = pw;  d = dpw; off = idx - WC6; }
  float4 v = ((const float4*)s)[off];
  union { short sh[4]; int2 p; } r;
  r.sh[0] = f2bf(v.x); r.sh[1] = f2bf(v.y);
  r.sh[2] = f2bf(v.z); r.sh[3] = f2bf(v.w);
  ((int2*)d)[off] = r.p;
}

// ---------------------------------------------------------------------------
// Instance-norm statistics over the time axis (L) of x (B,L,DV) fp32.
// ---------------------------------------------------------------------------
__global__ __launch_bounds__(256)
void stats_k(const float* __restrict__ x, float* __restrict__ means,
             float* __restrict__ stdev, float* __restrict__ rstd,
             float* __restrict__ xlast)
{
  int d = blockIdx.x * 256 + threadIdx.x;       // 0..511
  int b = blockIdx.y;
  const float* xp = x + (size_t)b * L_ * DV_ + d;
  float s = 0.f, ss = 0.f;
  for (int l = 0; l < L_; l++) {
    float v = xp[(size_t)l * DV_];
    s += v; ss += v * v;
  }
  float mu = s / (float)L_;
  float var = ss / (float)L_ - mu * mu;
  float sd = sqrtf(var + 1e-5f);
  float rs = 1.f / sd;
  int idx = b * DV_ + d;
  means[idx] = mu; stdev[idx] = sd; rstd[idx] = rs;
  xlast[idx] = (xp[(size_t)(L_ - 1) * DV_] - mu) * rs;
}

// ---------------------------------------------------------------------------
// Normalize + transpose: xnT[b,d,l] = (x[b,l,d]-mu[b,d])*rstd[b,d]  (bf16)
// ---------------------------------------------------------------------------
__global__ __launch_bounds__(256)
void tnorm_k(const float* __restrict__ x, const float* __restrict__ means,
             const float* __restrict__ rstd, short* __restrict__ xnT)
{
  __shared__ float tile[64][65];
  const int t = threadIdx.x;
  const int j = t & 63;
  const int i0 = t >> 6;                 // 0..3
  const int bz = blockIdx.z;
  const int l0 = blockIdx.y << 6;
  const int d0 = blockIdx.x << 6;
  const float* xp = x + ((size_t)bz * L_ + l0) * DV_ + d0;
  #pragma unroll
  for (int i = i0; i < 64; i += 4) tile[i][j] = xp[(size_t)i * DV_ + j];
  __syncthreads();
  short* op = xnT + ((size_t)bz * DV_ + d0) * L_ + l0;
  const int sb = bz * DV_ + d0;
  #pragma unroll
  for (int i = i0; i < 64; i += 4) {
    float mu = means[sb + i];
    float rs = rstd[sb + i];
    op[(size_t)i * L_ + j] = f2bf((tile[j][i] - mu) * rs);
  }
}

// ---------------------------------------------------------------------------
// Fused LayerNorm: optionally h += add (+ abias) in place, then LN -> bf16.
// ADD: 0 = plain, 1 = h += bf16 add, 2 = h += bf16 add + fp32 bias[col].
// ---------------------------------------------------------------------------
template <int ADD>
__global__ __launch_bounds__(256)
void ln_k(float* __restrict__ X, const short* __restrict__ add,
          const float* __restrict__ abias,
          const float* __restrict__ g, const float* __restrict__ b,
          short* __restrict__ Y)
{
  int row = blockIdx.x;
  float* x = X + (size_t)row * DM_;
  int t = threadIdx.x;
  float v0 = x[t], v1 = x[t + 256];
  if constexpr (ADD >= 1) {
    v0 += bf2f(add[(size_t)row * DM_ + t]);
    v1 += bf2f(add[(size_t)row * DM_ + t + 256]);
    if constexpr (ADD == 2) { v0 += abias[t]; v1 += abias[t + 256]; }
    x[t] = v0; x[t + 256] = v1;
  }
  float s = v0 + v1, ss = v0 * v0 + v1 * v1;
  #pragma unroll
  for (int o = 1; o < 64; o <<= 1) { s += __shfl_xor(s, o); ss += __shfl_xor(ss, o); }
  __shared__ float sb[8];
  int wave = t >> 6, lane = t & 63;
  if (lane == 0) { sb[wave] = s; sb[4 + wave] = ss; }
  __syncthreads();
  s = sb[0] + sb[1] + sb[2] + sb[3];
  ss = sb[4] + sb[5] + sb[6] + sb[7];
  float mu = s / (float)DM_;
  float var = ss / (float)DM_ - mu * mu;
  float rs = rsqrtf(var + 1e-5f);
  Y[(size_t)row * DM_ + t]       = f2bf((v0 - mu) * rs * g[t]       + b[t]);
  Y[(size_t)row * DM_ + t + 256] = f2bf((v1 - mu) * rs * g[t + 256] + b[t + 256]);
}

// ---------------------------------------------------------------------------
// Depthwise causal conv (DC=4 taps) + bias + silu.  REV templated.
// ---------------------------------------------------------------------------
template <int REV>
__global__ __launch_bounds__(256)
void conv_k(const short* __restrict__ xz, const float* __restrict__ w,
            const float* __restrict__ cb, short* __restrict__ xc)
{
  int idx = blockIdx.x * 256 + threadIdx.x;   // over B*S*DI
  int i = idx & (DI_ - 1);
  int bs = idx >> 10;                         // b*S + t
  int tt0 = bs & (S_ - 1);
  int b = bs >> 9;
  const short* u = xz + (size_t)b * S_ * (2 * DI_) + i;   // row stride 2*DI
  float acc = cb[i];
  #pragma unroll
  for (int k = 0; k < DC_; k++) {
    int tt = REV ? (tt0 + (DC_ - 1) - k) : (tt0 - (DC_ - 1) + k);
    if (tt >= 0 && tt < S_)
      acc += w[i * DC_ + k] * bf2f(u[(size_t)tt * (2 * DI_)]);
  }
  float sig = 1.f / (1.f + __expf(-acc));
  xc[idx] = f2bf(acc * sig);
}

// ---------------------------------------------------------------------------
// Chunked selective scan: state dim split 4-ways across adjacent lanes
// (thread (b,i,q) owns states n=4q..4q+3); grid 2048 blocks for occupancy.
// ---------------------------------------------------------------------------
template <int REV>
__global__ __launch_bounds__(256)
void scan_p1(const unsigned short* __restrict__ dt16, const short* __restrict__ xc,
             const short* __restrict__ xdbl, const float* __restrict__ A_log,
             unsigned short* __restrict__ part_h, unsigned short* __restrict__ part_A)
{
  const int gid = blockIdx.x * 256 + threadIdx.x;   // over B*DI*4
  const int q = gid & 3;                            // state quad
  const int i = (gid >> 2) & (DI_ - 1);
  const int b = gid >> 12;
  const int c = blockIdx.y;
  float Ai[4];
  const float* al = A_log + i * DS_ + q * 4;
  #pragma unroll
  for (int n = 0; n < 4; n++) Ai[n] = -__expf(al[n]);

  const int ti0 = REV ? (S_ - 1 - c * CS_) : (c * CS_);
  const unsigned short* pdt = dt16 + ((size_t)b * S_ + ti0) * DI_ + i;
  const short* pu = xc + ((size_t)b * S_ + ti0) * DI_ + i;
  const short* pbc = xdbl + (((size_t)b * S_ + ti0) << 6) + DTR_ + q * 4;
  const int sstep = REV ? -DI_ : DI_;
  const int sbc = REV ? -64 : 64;

  float h[4];
  #pragma unroll
  for (int n = 0; n < 4; n++) h[n] = 0.f;
  float dsum = 0.f;

  #pragma unroll 4
  for (int sl = 0; sl < CS_; sl++) {
    float dtv = h2f(*pdt);
    float u = bf2f(*pu);
    bf16x4 vB = *(const bf16x4*)pbc;
    float du = dtv * u;
    dsum += dtv;
    #pragma unroll
    for (int n = 0; n < 4; n++) {
      float dA = __expf(dtv * Ai[n]);
      h[n] = dA * h[n] + du * bf2f(vB[n]);
    }
    pdt += sstep; pu += sstep; pbc += sbc;
  }
  union { unsigned short s[4]; int2 v; } uh, ua;
  #pragma unroll
  for (int n = 0; n < 4; n++) {
    uh.s[n] = f2h(h[n]);
    ua.s[n] = f2h(__expf(Ai[n] * dsum));   // exact: prod exp(dt*A)=exp(A*sum dt)
  }
  const size_t ix = ((((size_t)c * B_ + b) * DI_ + i) << 4) + (q << 2);
  *(int2*)(part_h + ix) = uh.v;
  *(int2*)(part_A + ix) = ua.v;
}

__global__ __launch_bounds__(256)
void scan_p2(unsigned short* __restrict__ part_h,
             const unsigned short* __restrict__ part_A)
{
  const size_t gid = (size_t)blockIdx.x * 256 + threadIdx.x;   // B*DI*DS
  const size_t stride = (size_t)B_ * DI_ * DS_;
  float hin = 0.f;
  #pragma unroll
  for (int c = 0; c < CH_; c++) {
    size_t ix = (size_t)c * stride + gid;
    float hh = h2f(part_h[ix]);
    float pA = h2f(part_A[ix]);
    part_h[ix] = f2h(hin);            // becomes chunk c's incoming state
    hin = hh + pA * hin;
  }
}

// y may alias dt16 (element-exact same indices) — no __restrict__ on those.
template <int REV>
__global__ __launch_bounds__(256)
void scan_p3(const unsigned short* dt16, const short* __restrict__ xc,
             const short* __restrict__ xdbl, const short* __restrict__ xz,
             const float* __restrict__ A_log, const float* __restrict__ Dp,
             const unsigned short* __restrict__ part_h, short* y)
{
  const int gid = blockIdx.x * 256 + threadIdx.x;   // over B*DI*4
  const int q = gid & 3;                            // state quad
  const int i = (gid >> 2) & (DI_ - 1);
  const int b = gid >> 12;
  const int c = blockIdx.y;
  float Ai[4];
  const float* al = A_log + i * DS_ + q * 4;
  #pragma unroll
  for (int n = 0; n < 4; n++) Ai[n] = -__expf(al[n]);
  const float Di = Dp[i];

  float h[4];
  {
    const size_t ix = ((((size_t)c * B_ + b) * DI_ + i) << 4) + (q << 2);
    union { unsigned short s[4]; int2 v; } uh;
    uh.v = *(const int2*)(part_h + ix);
    #pragma unroll
    for (int n = 0; n < 4; n++) h[n] = h2f(uh.s[n]);
  }

  const int ti0 = REV ? (S_ - 1 - c * CS_) : (c * CS_);
  const unsigned short* pdt = dt16 + ((size_t)b * S_ + ti0) * DI_ + i;
  const short* pu = xc + ((size_t)b * S_ + ti0) * DI_ + i;
  const short* pbc = xdbl + (((size_t)b * S_ + ti0) << 6) + DTR_ + q * 4;
  const short* pz = xz + ((size_t)b * S_ + ti0) * (2 * DI_) + DI_ + i;
  short* py = y + ((size_t)b * S_ + ti0) * DI_ + i;
  const int sstep = REV ? -DI_ : DI_;
  const int sbc = REV ? -64 : 64;
  const int sz = REV ? -(2 * DI_) : (2 * DI_);

  #pragma unroll 4
  for (int sl = 0; sl < CS_; sl++) {
    float dtv = h2f(*pdt);
    float u = bf2f(*pu);
    bf16x4 vB = *(const bf16x4*)pbc;
    bf16x4 vC = *(const bf16x4*)(pbc + DS_);
    float zv = bf2f(*pz);
    float du = dtv * u;
    float yp = 0.f;
    #pragma unroll
    for (int n = 0; n < 4; n++) {
      float dA = __expf(dtv * Ai[n]);
      h[n] = dA * h[n] + du * bf2f(vB[n]);
      yp += h[n] * bf2f(vC[n]);
    }
    yp += __shfl_xor(yp, 1);
    yp += __shfl_xor(yp, 2);            // quad-wide sum over all 16 states
    float sil = zv / (1.f + __expf(-zv));
    float yv = (yp + u * Di) * sil;
    if (q == 0) *py = f2bf(yv);
    pdt += sstep; pu += sstep; pbc += sbc; pz += sz; py += sstep;
  }
}

// ---------------------------------------------------------------------------
// bf16 MFMA GEMM: C[M,N] = A[M,K] * W[N,K]^T, fp32 accum.  A and W both bf16
// (weights pre-converted once by wcvt_k).  Split-source concat-K.  Double-
// buffered LDS, lgkm-only barrier, XOR swizzle, 2x2 waves.  TWO slabs of
// register prefetch in flight; the two in-flight slabs live in STATICALLY
// NAMED register sets (arA/wvA = odd slabs, arB/wvB = even slabs) selected
// by a wave-uniform branch on kb&1 — rule #20: a runtime-indexed register
// array would be demoted to scratch (round-2 regression: 275 MB scratch
// writes/dispatch).
// ---------------------------------------------------------------------------
enum { EPI_F32_BIAS, EPI_BF16, EPI_F16_SOFTPLUS, EPI_HALF_BF16, EPI_GELU,
       EPI_PROJ };

template <int EPI, int BM, int BN, int BK>
__global__ __launch_bounds__(256)
void gemm_k(const short* __restrict__ A0, const short* __restrict__ A1,
            const short* __restrict__ W0, const short* __restrict__ W1,
            int khalf, int N, int K, int lda, int ldw,
            float* __restrict__ Cf, short* __restrict__ Cb, int ldc,
            const float* __restrict__ bias,
            const float* __restrict__ xlast, const float* __restrict__ stdev,
            const float* __restrict__ means)
{
  constexpr int MT = BM / 32;           // 16-row m-tiles per wave
  constexpr int NT = BN / 32;
  constexpr int KS = BK / 32;
  constexpr int CHK = BK / 8;           // 16B chunks per row
  constexpr int MSK = CHK - 1;
  constexpr int NA = (BM * CHK) / 256;
  constexpr int NW = (BN * CHK) / 256;
  __shared__ __align__(16) short As[2][BM * BK];
  __shared__ __align__(16) short Ws[2][BN * BK];
  const int tid = threadIdx.x;
  const int m0 = blockIdx.x * BM;       // fastest dim = m (XCD locality of A)
  const int n0 = blockIdx.y * BN;
  const int wave = tid >> 6, lane = tid & 63;
  const int wm = (wave & 1) * (BM / 2), wn = (wave >> 1) * (BN / 2);
  const int quad = lane >> 4, l16 = lane & 15;

  f32x4 acc[MT][NT] = {};

  size_t aoff[NA]; int apos[NA];
  #pragma unroll
  for (int j = 0; j < NA; j++) {
    int id = tid + j * 256;
    int r = id / CHK, q = id % CHK;
    aoff[j] = (size_t)(m0 + r) * lda + q * 8;
    apos[j] = r * BK + ((q ^ (r & MSK)) << 3);
  }
  size_t woff[NW]; int wpos[NW];
  #pragma unroll
  for (int j = 0; j < NW; j++) {
    int id = tid + j * 256;
    int r = id / CHK, q = id % CHK;
    int wr = n0 + r; if (wr > N - 1) wr = N - 1;
    woff[j] = (size_t)wr * ldw + q * 8;
    wpos[j] = r * BK + ((q ^ (r & MSK)) << 3);
  }

  const int KB = K / BK;
  int4 arA[NA], wvA[NW], arB[NA], wvB[NW];

  // prologue: slab 0 -> LDS[0] direct; arA <- slab 1; arB <- slab 2.
  #pragma unroll
  for (int j = 0; j < NA; j++) arA[j] = *(const int4*)(A0 + aoff[j]);
  #pragma unroll
  for (int j = 0; j < NW; j++) wvA[j] = *(const int4*)(W0 + woff[j]);
  #pragma unroll
  for (int j = 0; j < NA; j++) *(int4*)(&As[0][0] + apos[j]) = arA[j];
  #pragma unroll
  for (int j = 0; j < NW; j++) *(int4*)(&Ws[0][0] + wpos[j]) = wvA[j];
  if (KB > 1) {
    const short* Ab = (BK < khalf) ? A0 + BK : A1 + (BK - khalf);
    const short* Wb = (BK < khalf) ? W0 + BK : W1 + (BK - khalf);
    #pragma unroll
    for (int j = 0; j < NA; j++) arA[j] = *(const int4*)(Ab + aoff[j]);
    #pragma unroll
    for (int j = 0; j < NW; j++) wvA[j] = *(const int4*)(Wb + woff[j]);
  }
  if (KB > 2) {
    const int k0 = 2 * BK;
    const short* Ab = (k0 < khalf) ? A0 + k0 : A1 + (k0 - khalf);
    const short* Wb = (k0 < khalf) ? W0 + k0 : W1 + (k0 - khalf);
    #pragma unroll
    for (int j = 0; j < NA; j++) arB[j] = *(const int4*)(Ab + aoff[j]);
    #pragma unroll
    for (int j = 0; j < NW; j++) wvB[j] = *(const int4*)(Wb + woff[j]);
  }
  lds_barrier();

#define GEMM_STAGE(AR, WV)                                                    \
  {                                                                           \
    _Pragma("unroll")                                                         \
    for (int j = 0; j < NA; j++) *(int4*)(&As[cur ^ 1][0] + apos[j]) = AR[j]; \
    _Pragma("unroll")                                                         \
    for (int j = 0; j < NW; j++) *(int4*)(&Ws[cur ^ 1][0] + wpos[j]) = WV[j]; \
    if (kb + 3 < KB) {                                                        \
      const int k0 = (kb + 3) * BK;                                           \
      const short* Ab = (k0 < khalf) ? A0 + k0 : A1 + (k0 - khalf);           \
      const short* Wb = (k0 < khalf) ? W0 + k0 : W1 + (k0 - khalf);           \
      _Pragma("unroll")                                                       \
      for (int j = 0; j < NA; j++) AR[j] = *(const int4*)(Ab + aoff[j]);      \
      _Pragma("unroll")                                                       \
      for (int j = 0; j < NW; j++) WV[j] = *(const int4*)(Wb + woff[j]);      \
    }                                                                         \
  }

  for (int kb = 0; kb < KB; kb++) {
    const int cur = kb & 1;
    bf16x8 af[MT][KS], bfr[NT][KS];
    #pragma unroll
    for (int mt = 0; mt < MT; mt++)
      #pragma unroll
      for (int st = 0; st < KS; st++)
        af[mt][st] = *(const bf16x8*)(&As[cur][0] + (wm + mt * 16 + l16) * BK +
                                      (((st * 4 + quad) ^ (l16 & MSK)) << 3));
    #pragma unroll
    for (int nt = 0; nt < NT; nt++)
      #pragma unroll
      for (int st = 0; st < KS; st++)
        bfr[nt][st] = *(const bf16x8*)(&Ws[cur][0] + (wn + nt * 16 + l16) * BK +
                                       (((st * 4 + quad) ^ (l16 & MSK)) << 3));
    if (kb + 1 < KB) {
      if (cur == 0) { GEMM_STAGE(arA, wvA); }
      else          { GEMM_STAGE(arB, wvB); }
    }
    #pragma unroll
    for (int st = 0; st < KS; st++)
      #pragma unroll
      for (int mt = 0; mt < MT; mt++)
        #pragma unroll
        for (int nt = 0; nt < NT; nt++)
          acc[mt][nt] = __builtin_amdgcn_mfma_f32_16x16x32_bf16(
              af[mt][st], bfr[nt][st], acc[mt][nt], 0, 0, 0);
    lds_barrier();
  }
#undef GEMM_STAGE

  #pragma unroll
  for (int mt = 0; mt < MT; mt++) {
    #pragma unroll
    for (int nt = 0; nt < NT; nt++) {
      int n = n0 + wn + nt * 16 + l16;
      if (n >= N) continue;
      #pragma unroll
      for (int r = 0; r < 4; r++) {
        int m = m0 + wm + mt * 16 + quad * 4 + r;
        float v = acc[mt][nt][r];
        if constexpr (EPI == EPI_F32_BIAS) {
          Cf[(size_t)m * ldc + n] = v + bias[n];
        } else if constexpr (EPI == EPI_BF16) {
          Cb[(size_t)m * ldc + n] = f2bf(v);
        } else if constexpr (EPI == EPI_F16_SOFTPLUS) {
          float tt = v + bias[n];
          float sp = (tt > 20.f) ? tt : log1pf(__expf(tt));
          ((unsigned short*)Cb)[(size_t)m * ldc + n] = f2h(sp);
        } else if constexpr (EPI == EPI_HALF_BF16) {
          Cb[(size_t)m * ldc + n] = f2bf(0.5f * v);
        } else if constexpr (EPI == EPI_GELU) {
          float tt = v + bias[n];
          Cb[(size_t)m * ldc + n] = f2bf(0.5f * tt * (1.f + erff(tt * 0.70710678118f)));
        } else if constexpr (EPI == EPI_PROJ) {
          int bb = m >> 9, d = m & 511;
          float tt = v + bias[n] + xlast[m];
          tt = tt * stdev[m] + means[m];
          Cf[((size_t)bb * PL_ + n) * DV_ + d] = tt;
        }
      }
    }
  }
}

// ---------------------------------------------------------------------------
extern "C" void kernel_launch(void* const* d_in, const int* in_sizes, int n_in,
                              void* d_out, int out_size, void* d_ws, size_t ws_size,
                              hipStream_t stream)
{
  (void)in_sizes; (void)n_in; (void)out_size; (void)ws_size;
  const float* x        = (const float*)d_in[0];
  const float* emb_w    = (const float*)d_in[1];
  const float* emb_b    = (const float*)d_in[2];
  const float* ln_g     = (const float*)d_in[3];
  const float* ln_b     = (const float*)d_in[4];
  const float* m_in_w   = (const float*)d_in[5];
  const float* m_conv_w = (const float*)d_in[6];
  const float* m_conv_b = (const float*)d_in[7];
  const float* m_xp_w   = (const float*)d_in[8];
  const float* m_dt_w   = (const float*)d_in[9];
  const float* m_dt_b   = (const float*)d_in[10];
  const float* m_A_log  = (const float*)d_in[11];
  const float* m_D      = (const float*)d_in[12];
  const float* m_out_w  = (const float*)d_in[13];
  const float* ffn_ln_g = (const float*)d_in[14];
  const float* ffn_ln_b = (const float*)d_in[15];
  const float* ffn_w1   = (const float*)d_in[16];
  const float* ffn_b1   = (const float*)d_in[17];
  const float* ffn_w2   = (const float*)d_in[18];
  const float* ffn_b2   = (const float*)d_in[19];
  const float* enc_g    = (const float*)d_in[20];
  const float* enc_b    = (const float*)d_in[21];
  const float* proj_w   = (const float*)d_in[22];
  const float* proj_b   = (const float*)d_in[23];
  float* out = (float*)d_out;

  char* ws = (char*)d_ws;
  const size_t MB = 1024 * 1024;
  float* h      = (float*)(ws + 0);        //  8 MB fp32 residual stream
  short* hn     = (short*)(ws + 8 * MB);   //  4 MB LN output bf16
  short* xz     = (short*)(ws + 12 * MB);  // 16 MB [M][2048] per-dir
  short* xc     = (short*)(ws + 28 * MB);  //  8 MB [M][1024] per-dir
  short* xdbl   = (short*)(ws + 36 * MB);  // .5 MB [M][64]
  float* stats  = (float*)(ws + 36 * MB + 512 * 1024);          // 64 KB
  unsigned short* dtb = (unsigned short*)(ws + 37 * MB); // 8 MB fp16 dt; scan_p3 dir1 writes y in place
  unsigned short* part_h = (unsigned short*)(ws + 45 * MB);     // 4 MB (scan only)
  unsigned short* part_A = (unsigned short*)(ws + 49 * MB);     // 4 MB (scan only)
  short* vtmp   = (short*)(ws + 47 * MB);  // 4 MB bf16 mamba out (after scans done)
  short* ftmp   = (short*)(ws + 47 * MB);  // 4 MB bf16 ffn2 out (aliases vtmp, sequential)
  short* yact0  = (short*)(ws + 53 * MB);  //  8 MB y(dir0); xnT aliases pre-layer
  short* xnT    = (short*)(ws + 53 * MB);
  float* means = stats, *stdevp = stats + 4096, *rstd = stats + 8192, *xlast = stats + 12288;

  // bf16 weight pool @ 61 MB (~32 MB total, high-water ~94 MB)
  short* emb_wb = (short*)(ws + 61 * MB);
  short* in_wb  = emb_wb + 262144;      // 6 x 2048x512
  short* xp_wb  = in_wb  + 6291456;     // 6 x 64x1024
  short* dt_wb  = xp_wb  + 393216;      // 6 x 1024x32
  short* out_wb = dt_wb  + 196608;      // 6 x 512x1024
  short* w1b    = out_wb + 3145728;     // 3 x 2048x512
  short* w2b    = w1b    + 3145728;     // 3 x 512x2048
  short* projb  = w2b    + 3145728;     // 96x512

  dim3 blk(256);
  const int NOSPLIT = 1 << 30;

  wcvt_k<<<dim3(16240), blk, 0, stream>>>(
      emb_w, m_in_w, m_xp_w, m_dt_w, m_out_w, ffn_w1, ffn_w2, proj_w,
      emb_wb, in_wb, xp_wb, dt_wb, out_wb, w1b, w2b, projb);

  stats_k<<<dim3(2, B_), blk, 0, stream>>>(x, means, stdevp, rstd, xlast);
  tnorm_k<<<dim3(8, 8, B_), blk, 0, stream>>>(x, means, rstd, xnT);
  // emb: M=4096, N=512, K=512 — 64x32 BK=64, grid (64, 16)
  gemm_k<EPI_F32_BIAS, 64, 32, 64><<<dim3(64, 16), blk, 0, stream>>>(
      xnT, xnT, emb_wb, emb_wb, NOSPLIT, DM_, L_, L_, L_,
      h, nullptr, DM_, emb_b, nullptr, nullptr, nullptr);

  for (int il = 0; il < EL_; il++) {
    if (il == 0)
      ln_k<0><<<dim3(4096), blk, 0, stream>>>(h, nullptr, nullptr, ln_g, ln_b, hn);
    else
      ln_k<2><<<dim3(4096), blk, 0, stream>>>(h, ftmp, ffn_b2 + (il - 1) * DM_,
          ln_g + il * DM_, ln_b + il * DM_, hn);
    for (int dir = 0; dir < 2; dir++) {
      int mod = 2 * il + dir;
      // in-proj: N=2048, K=512 — 64x128 BK=32, grid (64, 16) = 1024 blocks
      gemm_k<EPI_BF16, 64, 128, 32><<<dim3(64, 16), blk, 0, stream>>>(
          hn, hn, in_wb + (size_t)mod * 2 * DI_ * DM_,
          in_wb + (size_t)mod * 2 * DI_ * DM_, NOSPLIT, 2 * DI_, DM_, DM_, DM_,
          nullptr, xz, 2 * DI_, nullptr, nullptr, nullptr, nullptr);
      if (dir == 0)
        conv_k<0><<<dim3(16384), blk, 0, stream>>>(
            xz, m_conv_w + (size_t)mod * DI_ * DC_, m_conv_b + (size_t)mod * DI_, xc);
      else
        conv_k<1><<<dim3(16384), blk, 0, stream>>>(
            xz, m_conv_w + (size_t)mod * DI_ * DC_, m_conv_b + (size_t)mod * DI_, xc);
      // xdbl: N=64, K=1024 — 32x32 BK=64, grid (128, 2)
      gemm_k<EPI_BF16, 32, 32, 64><<<dim3(128, 2), blk, 0, stream>>>(
          xc, xc, xp_wb + (size_t)mod * (DTR_ + 2 * DS_) * DI_,
          xp_wb + (size_t)mod * (DTR_ + 2 * DS_) * DI_, NOSPLIT,
          DTR_ + 2 * DS_, DI_, DI_, DI_,
          nullptr, xdbl, DTR_ + 2 * DS_, nullptr, nullptr, nullptr, nullptr);
      // dt: N=1024, K=32 — 64x64 BK=32, grid (64, 16)
      gemm_k<EPI_F16_SOFTPLUS, 64, 64, 32><<<dim3(64, 16), blk, 0, stream>>>(
          xdbl, xdbl, dt_wb + (size_t)mod * DI_ * DTR_,
          dt_wb + (size_t)mod * DI_ * DTR_, NOSPLIT, DI_, DTR_, DTR_ + 2 * DS_, DTR_,
          nullptr, (short*)dtb, DI_, m_dt_b + (size_t)mod * DI_, nullptr, nullptr, nullptr);
      const float* Alog = m_A_log + (size_t)mod * DI_ * DS_;
      const float* Dp = m_D + (size_t)mod * DI_;
      short* ydst = (dir == 0) ? yact0 : (short*)dtb;   // dir1: in-place over dtb
      if (dir == 0) {
        scan_p1<0><<<dim3(128, CH_), blk, 0, stream>>>(dtb, xc, xdbl, Alog, part_h, part_A);
        scan_p2<<<dim3(512), blk, 0, stream>>>(part_h, part_A);
        scan_p3<0><<<dim3(128, CH_), blk, 0, stream>>>(dtb, xc, xdbl, xz, Alog, Dp, part_h, ydst);
      } else {
        scan_p1<1><<<dim3(128, CH_), blk, 0, stream>>>(dtb, xc, xdbl, Alog, part_h, part_A);
        scan_p2<<<dim3(512), blk, 0, stream>>>(part_h, part_A);
        scan_p3<1><<<dim3(128, CH_), blk, 0, stream>>>(dtb, xc, xdbl, xz, Alog, Dp, part_h, ydst);
      }
    }
    // out-proj (concat-K): vtmp = 0.5*(yf.Wf^T + yb.Wb^T) — 64x32 BK=64, grid (64,16)
    gemm_k<EPI_HALF_BF16, 64, 32, 64><<<dim3(64, 16), blk, 0, stream>>>(
        yact0, (const short*)dtb,
        out_wb + (size_t)(2 * il) * DM_ * DI_,
        out_wb + (size_t)(2 * il + 1) * DM_ * DI_,
        DI_, DM_, 2 * DI_, DI_, DI_,
        nullptr, vtmp, DM_, nullptr, nullptr, nullptr, nullptr);
    // fused: h += vtmp, then LN
    ln_k<1><<<dim3(4096), blk, 0, stream>>>(h, vtmp, nullptr,
        ffn_ln_g + il * DM_, ffn_ln_b + il * DM_, hn);
    // ffn1: N=2048, K=512 — 64x128 BK=32, grid (64, 16)
    gemm_k<EPI_GELU, 64, 128, 32><<<dim3(64, 16), blk, 0, stream>>>(
        hn, hn, w1b + (size_t)il * 4 * DM_ * DM_,
        w1b + (size_t)il * 4 * DM_ * DM_, NOSPLIT, 4 * DM_, DM_, DM_, DM_,
        nullptr, xz, 4 * DM_, ffn_b1 + (size_t)il * 4 * DM_, nullptr, nullptr, nullptr);
    // ffn2: N=512, K=2048 — 64x32 BK=64, grid (64, 16); streaming bf16 out
    gemm_k<EPI_BF16, 64, 32, 64><<<dim3(64, 16), blk, 0, stream>>>(
        xz, xz, w2b + (size_t)il * DM_ * 4 * DM_,
        w2b + (size_t)il * DM_ * 4 * DM_, NOSPLIT, DM_, 4 * DM_, 4 * DM_, 4 * DM_,
        nullptr, ftmp, DM_, nullptr, nullptr, nullptr, nullptr);
    // h += ftmp + ffn_b2 happens in the next layer's LN (or enc-LN below)
  }

  ln_k<2><<<dim3(4096), blk, 0, stream>>>(h, ftmp, ffn_b2 + 2 * DM_,
      enc_g, enc_b, hn);
  // proj: N=96, K=512 — 64x32 BK=64, grid (64, 3)
  gemm_k<EPI_PROJ, 64, 32, 64><<<dim3(64, 3), blk, 0, stream>>>(
      hn, hn, projb, projb, NOSPLIT, PL_, DM_, DM_, DM_,
      out, nullptr, 0, proj_b, xlast, stdevp, means);
}

// Round 4
// 1176.778 us; speedup vs baseline: 1.7726x; 1.4784x over previous
//
#include <hip/hip_runtime.h>
#include <hip/hip_bf16.h>
#include <math.h>

#define B_ 8
#define L_ 512
#define DV_ 512
#define DM_ 512
#define PL_ 96
#define EL_ 3
#define DS_ 16
#define DC_ 4
#define DI_ 1024
#define DTR_ 32
#define S_ 512
#define CH_ 16         // scan chunks
#define CS_ 32         // steps per chunk

typedef float f32x4 __attribute__((ext_vector_type(4)));
typedef short bf16x8 __attribute__((ext_vector_type(8)));
typedef short bf16x4 __attribute__((ext_vector_type(4)));

__device__ __forceinline__ float bf2f(short s) {
  unsigned u = ((unsigned)(unsigned short)s) << 16;
  return __builtin_bit_cast(float, u);
}
__device__ __forceinline__ short f2bf(float f) {
  unsigned u = __builtin_bit_cast(unsigned, f);
  u = u + 0x7FFFu + ((u >> 16) & 1u);   // RNE
  return (short)(u >> 16);
}
__device__ __forceinline__ float h2f(unsigned short u) {
  _Float16 h = __builtin_bit_cast(_Float16, u);
  return (float)h;
}
__device__ __forceinline__ unsigned short f2h(float f) {
  _Float16 h = (_Float16)f;
  return __builtin_bit_cast(unsigned short, h);
}

// global -> LDS DMA, 16B per lane.  LDS dest is wave-uniform base + lane*16.
__device__ __forceinline__ void gload16(const short* g, short* l) {
  __builtin_amdgcn_global_load_lds(
      (const __attribute__((address_space(1))) void*)g,
      (__attribute__((address_space(3))) void*)l, 16, 0, 0);
}

// ---------------------------------------------------------------------------
// One-shot fp32 -> bf16 conversion of ALL GEMM weights into workspace.
// Segment bounds in float4 units (compile-time).
// ---------------------------------------------------------------------------
#define WC0 65536                 // emb_w      512*512
#define WC1 (WC0 + 1572864)       // m_in_w     6*2048*512
#define WC2 (WC1 + 98304)         // m_xp_w     6*64*1024
#define WC3 (WC2 + 49152)         // m_dt_w     6*1024*32
#define WC4 (WC3 + 786432)        // m_out_w    6*512*1024
#define WC5 (WC4 + 786432)        // ffn_w1     3*2048*512
#define WC6 (WC5 + 786432)        // ffn_w2     3*512*2048
#define WC7 (WC6 + 12288)        // proj_w     96*512
// WC7 = 4157440 float4s; grid = 16240 * 256 exactly.

__global__ __launch_bounds__(256)
void wcvt_k(const float* __restrict__ e, const float* __restrict__ iw,
            const float* __restrict__ xp, const float* __restrict__ dtw,
            const float* __restrict__ ow, const float* __restrict__ w1,
            const float* __restrict__ w2, const float* __restrict__ pw,
            short* __restrict__ de, short* __restrict__ di,
            short* __restrict__ dxp, short* __restrict__ ddt,
            short* __restrict__ dow, short* __restrict__ dw1,
            short* __restrict__ dw2, short* __restrict__ dpw)
{
  int idx = blockIdx.x * 256 + threadIdx.x;
  const float* s; short* d; int off;
  if (idx < WC0)      { s = e;   d = de;  off = idx; }
  else if (idx < WC1) { s = iw;  d = di;  off = idx - WC0; }
  else if (idx < WC2) { s = xp;  d = dxp; off = idx - WC1; }
  else if (idx < WC3) { s = dtw; d = ddt; off = idx - WC2; }
  else if (idx < WC4) { s = ow;  d = dow; off = idx - WC3; }
  else if (idx < WC5) { s = w1;  d = dw1; off = idx - WC4; }
  else if (idx < WC6) { s = w2;  d = dw2; off = idx - WC5; }
  else                { s = pw;  d = dpw; off = idx - WC6; }
  float4 v = ((const float4*)s)[off];
  union { short sh[4]; int2 p; } r;
  r.sh[0] = f2bf(v.x); r.sh[1] = f2bf(v.y);
  r.sh[2] = f2bf(v.z); r.sh[3] = f2bf(v.w);
  ((int2*)d)[off] = r.p;
}

// ---------------------------------------------------------------------------
// Instance-norm statistics over the time axis (L) of x (B,L,DV) fp32.
// ---------------------------------------------------------------------------
__global__ __launch_bounds__(256)
void stats_k(const float* __restrict__ x, float* __restrict__ means,
             float* __restrict__ stdev, float* __restrict__ rstd,
             float* __restrict__ xlast)
{
  int d = blockIdx.x * 256 + threadIdx.x;       // 0..511
  int b = blockIdx.y;
  const float* xp = x + (size_t)b * L_ * DV_ + d;
  float s = 0.f, ss = 0.f;
  for (int l = 0; l < L_; l++) {
    float v = xp[(size_t)l * DV_];
    s += v; ss += v * v;
  }
  float mu = s / (float)L_;
  float var = ss / (float)L_ - mu * mu;
  float sd = sqrtf(var + 1e-5f);
  float rs = 1.f / sd;
  int idx = b * DV_ + d;
  means[idx] = mu; stdev[idx] = sd; rstd[idx] = rs;
  xlast[idx] = (xp[(size_t)(L_ - 1) * DV_] - mu) * rs;
}

// ---------------------------------------------------------------------------
// Normalize + transpose: xnT[b,d,l] = (x[b,l,d]-mu[b,d])*rstd[b,d]  (bf16)
// ---------------------------------------------------------------------------
__global__ __launch_bounds__(256)
void tnorm_k(const float* __restrict__ x, const float* __restrict__ means,
             const float* __restrict__ rstd, short* __restrict__ xnT)
{
  __shared__ float tile[64][65];
  const int t = threadIdx.x;
  const int j = t & 63;
  const int i0 = t >> 6;                 // 0..3
  const int bz = blockIdx.z;
  const int l0 = blockIdx.y << 6;
  const int d0 = blockIdx.x << 6;
  const float* xp = x + ((size_t)bz * L_ + l0) * DV_ + d0;
  #pragma unroll
  for (int i = i0; i < 64; i += 4) tile[i][j] = xp[(size_t)i * DV_ + j];
  __syncthreads();
  short* op = xnT + ((size_t)bz * DV_ + d0) * L_ + l0;
  const int sb = bz * DV_ + d0;
  #pragma unroll
  for (int i = i0; i < 64; i += 4) {
    float mu = means[sb + i];
    float rs = rstd[sb + i];
    op[(size_t)i * L_ + j] = f2bf((tile[j][i] - mu) * rs);
  }
}

// ---------------------------------------------------------------------------
// Fused LayerNorm: optionally h += add (+ abias) in place, then LN -> bf16.
// ADD: 0 = plain, 1 = h += bf16 add, 2 = h += bf16 add + fp32 bias[col].
// ---------------------------------------------------------------------------
template <int ADD>
__global__ __launch_bounds__(256)
void ln_k(float* __restrict__ X, const short* __restrict__ add,
          const float* __restrict__ abias,
          const float* __restrict__ g, const float* __restrict__ b,
          short* __restrict__ Y)
{
  int row = blockIdx.x;
  float* x = X + (size_t)row * DM_;
  int t = threadIdx.x;
  float v0 = x[t], v1 = x[t + 256];
  if constexpr (ADD >= 1) {
    v0 += bf2f(add[(size_t)row * DM_ + t]);
    v1 += bf2f(add[(size_t)row * DM_ + t + 256]);
    if constexpr (ADD == 2) { v0 += abias[t]; v1 += abias[t + 256]; }
    x[t] = v0; x[t + 256] = v1;
  }
  float s = v0 + v1, ss = v0 * v0 + v1 * v1;
  #pragma unroll
  for (int o = 1; o < 64; o <<= 1) { s += __shfl_xor(s, o); ss += __shfl_xor(ss, o); }
  __shared__ float sb[8];
  int wave = t >> 6, lane = t & 63;
  if (lane == 0) { sb[wave] = s; sb[4 + wave] = ss; }
  __syncthreads();
  s = sb[0] + sb[1] + sb[2] + sb[3];
  ss = sb[4] + sb[5] + sb[6] + sb[7];
  float mu = s / (float)DM_;
  float var = ss / (float)DM_ - mu * mu;
  float rs = rsqrtf(var + 1e-5f);
  Y[(size_t)row * DM_ + t]       = f2bf((v0 - mu) * rs * g[t]       + b[t]);
  Y[(size_t)row * DM_ + t + 256] = f2bf((v1 - mu) * rs * g[t + 256] + b[t + 256]);
}

// ---------------------------------------------------------------------------
// Depthwise causal conv (DC=4 taps) + bias + silu.  REV templated.
// ---------------------------------------------------------------------------
template <int REV>
__global__ __launch_bounds__(256)
void conv_k(const short* __restrict__ xz, const float* __restrict__ w,
            const float* __restrict__ cb, short* __restrict__ xc)
{
  int idx = blockIdx.x * 256 + threadIdx.x;   // over B*S*DI
  int i = idx & (DI_ - 1);
  int bs = idx >> 10;                         // b*S + t
  int tt0 = bs & (S_ - 1);
  int b = bs >> 9;
  const short* u = xz + (size_t)b * S_ * (2 * DI_) + i;   // row stride 2*DI
  float acc = cb[i];
  #pragma unroll
  for (int k = 0; k < DC_; k++) {
    int tt = REV ? (tt0 + (DC_ - 1) - k) : (tt0 - (DC_ - 1) + k);
    if (tt >= 0 && tt < S_)
      acc += w[i * DC_ + k] * bf2f(u[(size_t)tt * (2 * DI_)]);
  }
  float sig = 1.f / (1.f + __expf(-acc));
  xc[idx] = f2bf(acc * sig);
}

// ---------------------------------------------------------------------------
// Chunked selective scan: state dim split 4-ways across adjacent lanes
// (thread (b,i,q) owns states n=4q..4q+3); grid 2048 blocks for occupancy.
// ---------------------------------------------------------------------------
template <int REV>
__global__ __launch_bounds__(256)
void scan_p1(const unsigned short* __restrict__ dt16, const short* __restrict__ xc,
             const short* __restrict__ xdbl, const float* __restrict__ A_log,
             unsigned short* __restrict__ part_h, unsigned short* __restrict__ part_A)
{
  const int gid = blockIdx.x * 256 + threadIdx.x;   // over B*DI*4
  const int q = gid & 3;                            // state quad
  const int i = (gid >> 2) & (DI_ - 1);
  const int b = gid >> 12;
  const int c = blockIdx.y;
  float Ai[4];
  const float* al = A_log + i * DS_ + q * 4;
  #pragma unroll
  for (int n = 0; n < 4; n++) Ai[n] = -__expf(al[n]);

  const int ti0 = REV ? (S_ - 1 - c * CS_) : (c * CS_);
  const unsigned short* pdt = dt16 + ((size_t)b * S_ + ti0) * DI_ + i;
  const short* pu = xc + ((size_t)b * S_ + ti0) * DI_ + i;
  const short* pbc = xdbl + (((size_t)b * S_ + ti0) << 6) + DTR_ + q * 4;
  const int sstep = REV ? -DI_ : DI_;
  const int sbc = REV ? -64 : 64;

  float h[4];
  #pragma unroll
  for (int n = 0; n < 4; n++) h[n] = 0.f;
  float dsum = 0.f;

  #pragma unroll 4
  for (int sl = 0; sl < CS_; sl++) {
    float dtv = h2f(*pdt);
    float u = bf2f(*pu);
    bf16x4 vB = *(const bf16x4*)pbc;
    float du = dtv * u;
    dsum += dtv;
    #pragma unroll
    for (int n = 0; n < 4; n++) {
      float dA = __expf(dtv * Ai[n]);
      h[n] = dA * h[n] + du * bf2f(vB[n]);
    }
    pdt += sstep; pu += sstep; pbc += sbc;
  }
  union { unsigned short s[4]; int2 v; } uh, ua;
  #pragma unroll
  for (int n = 0; n < 4; n++) {
    uh.s[n] = f2h(h[n]);
    ua.s[n] = f2h(__expf(Ai[n] * dsum));   // exact: prod exp(dt*A)=exp(A*sum dt)
  }
  const size_t ix = ((((size_t)c * B_ + b) * DI_ + i) << 4) + (q << 2);
  *(int2*)(part_h + ix) = uh.v;
  *(int2*)(part_A + ix) = ua.v;
}

__global__ __launch_bounds__(256)
void scan_p2(unsigned short* __restrict__ part_h,
             const unsigned short* __restrict__ part_A)
{
  const size_t gid = (size_t)blockIdx.x * 256 + threadIdx.x;   // B*DI*DS
  const size_t stride = (size_t)B_ * DI_ * DS_;
  float hin = 0.f;
  #pragma unroll
  for (int c = 0; c < CH_; c++) {
    size_t ix = (size_t)c * stride + gid;
    float hh = h2f(part_h[ix]);
    float pA = h2f(part_A[ix]);
    part_h[ix] = f2h(hin);            // becomes chunk c's incoming state
    hin = hh + pA * hin;
  }
}

// y may alias dt16 (element-exact same indices) — no __restrict__ on those.
template <int REV>
__global__ __launch_bounds__(256)
void scan_p3(const unsigned short* dt16, const short* __restrict__ xc,
             const short* __restrict__ xdbl, const short* __restrict__ xz,
             const float* __restrict__ A_log, const float* __restrict__ Dp,
             const unsigned short* __restrict__ part_h, short* y)
{
  const int gid = blockIdx.x * 256 + threadIdx.x;   // over B*DI*4
  const int q = gid & 3;                            // state quad
  const int i = (gid >> 2) & (DI_ - 1);
  const int b = gid >> 12;
  const int c = blockIdx.y;
  float Ai[4];
  const float* al = A_log + i * DS_ + q * 4;
  #pragma unroll
  for (int n = 0; n < 4; n++) Ai[n] = -__expf(al[n]);
  const float Di = Dp[i];

  float h[4];
  {
    const size_t ix = ((((size_t)c * B_ + b) * DI_ + i) << 4) + (q << 2);
    union { unsigned short s[4]; int2 v; } uh;
    uh.v = *(const int2*)(part_h + ix);
    #pragma unroll
    for (int n = 0; n < 4; n++) h[n] = h2f(uh.s[n]);
  }

  const int ti0 = REV ? (S_ - 1 - c * CS_) : (c * CS_);
  const unsigned short* pdt = dt16 + ((size_t)b * S_ + ti0) * DI_ + i;
  const short* pu = xc + ((size_t)b * S_ + ti0) * DI_ + i;
  const short* pbc = xdbl + (((size_t)b * S_ + ti0) << 6) + DTR_ + q * 4;
  const short* pz = xz + ((size_t)b * S_ + ti0) * (2 * DI_) + DI_ + i;
  short* py = y + ((size_t)b * S_ + ti0) * DI_ + i;
  const int sstep = REV ? -DI_ : DI_;
  const int sbc = REV ? -64 : 64;
  const int sz = REV ? -(2 * DI_) : (2 * DI_);

  #pragma unroll 4
  for (int sl = 0; sl < CS_; sl++) {
    float dtv = h2f(*pdt);
    float u = bf2f(*pu);
    bf16x4 vB = *(const bf16x4*)pbc;
    bf16x4 vC = *(const bf16x4*)(pbc + DS_);
    float zv = bf2f(*pz);
    float du = dtv * u;
    float yp = 0.f;
    #pragma unroll
    for (int n = 0; n < 4; n++) {
      float dA = __expf(dtv * Ai[n]);
      h[n] = dA * h[n] + du * bf2f(vB[n]);
      yp += h[n] * bf2f(vC[n]);
    }
    yp += __shfl_xor(yp, 1);
    yp += __shfl_xor(yp, 2);            // quad-wide sum over all 16 states
    float sil = zv / (1.f + __expf(-zv));
    float yv = (yp + u * Di) * sil;
    if (q == 0) *py = f2bf(yv);
    pdt += sstep; pu += sstep; pbc += sbc; pz += sz; py += sstep;
  }
}

// ---------------------------------------------------------------------------
// bf16 MFMA GEMM: C[M,N] = A[M,K] * W[N,K]^T, fp32 accum.  A and W bf16
// (weights pre-converted by wcvt_k).  Staging via global_load_lds DMA —
// ZERO staging registers (rounds 2-3: register staging spilled to scratch,
// 126-275 MB writes/dispatch).  Swizzle moved to the GLOBAL source chunk
// index (rule #21: linear LDS dest + inverse-swizzled source); MFMA-side
// read formula unchanged from the validated kernel.  3 LDS buffers, 2 slabs
// in flight, raw s_barrier + counted vmcnt (T4: never drain to 0 in steady
// state).  Slab kb+2 is issued at the TOP of iter kb into buffer (kb-1)%3
// (last read in iter kb-1, barrier-separated -> race-free).
// ---------------------------------------------------------------------------
enum { EPI_F32_BIAS, EPI_BF16, EPI_F16_SOFTPLUS, EPI_HALF_BF16, EPI_GELU,
       EPI_PROJ };

template <int EPI, int BM, int BN, int BK>
__global__ __launch_bounds__(256)
void gemm_k(const short* __restrict__ A0, const short* __restrict__ A1,
            const short* __restrict__ W0, const short* __restrict__ W1,
            int khalf, int N, int K, int lda, int ldw,
            float* __restrict__ Cf, short* __restrict__ Cb, int ldc,
            const float* __restrict__ bias,
            const float* __restrict__ xlast, const float* __restrict__ stdev,
            const float* __restrict__ means)
{
  constexpr int MT = BM / 32;           // 16-row m-tiles per wave
  constexpr int NT = BN / 32;
  constexpr int KS = BK / 32;
  constexpr int CHK = BK / 8;           // 16B chunks per row
  constexpr int MSK = CHK - 1;
  constexpr int NA = (BM * CHK) / 256;  // DMA calls per wave, A slab
  constexpr int NW = (BN * CHK) / 256;  // DMA calls per wave, W slab
  constexpr int VC = NA + NW;           // vmem ops per slab per wave
  __shared__ __align__(16) short As[3][BM * BK];
  __shared__ __align__(16) short Ws[3][BN * BK];
  const int tid = threadIdx.x;
  const int m0 = blockIdx.x * BM;       // fastest dim = m (XCD locality of A)
  const int n0 = blockIdx.y * BN;
  const int wave = tid >> 6, lane = tid & 63;
  const int wm = (wave & 1) * (BM / 2), wn = (wave >> 1) * (BN / 2);
  const int quad = lane >> 4, l16 = lane & 15;

  f32x4 acc[MT][NT] = {};

  // Per-thread global offsets with the XOR swizzle folded into the SOURCE
  // chunk index; LDS destination is linear (id*16B).
  size_t aoff[NA];
  #pragma unroll
  for (int j = 0; j < NA; j++) {
    int id = j * 256 + tid;
    int r = id / CHK, qp = id % CHK;
    aoff[j] = (size_t)(m0 + r) * lda + ((qp ^ (r & MSK)) << 3);
  }
  size_t woff[NW];
  #pragma unroll
  for (int j = 0; j < NW; j++) {
    int id = j * 256 + tid;
    int r = id / CHK, qp = id % CHK;
    int wr = n0 + r; if (wr > N - 1) wr = N - 1;
    woff[j] = (size_t)wr * ldw + ((qp ^ (r & MSK)) << 3);
  }
  const int lbase = wave * 512;         // shorts; wave-uniform lane-0 base

  const int KB = K / BK;

  auto stage = [&](int slab, int bi) {
    const int k0 = slab * BK;
    const short* Ab = (k0 < khalf) ? A0 + k0 : A1 + (k0 - khalf);
    const short* Wb = (k0 < khalf) ? W0 + k0 : W1 + (k0 - khalf);
    #pragma unroll
    for (int j = 0; j < NA; j++)
      gload16(Ab + aoff[j], &As[bi][j * 2048 + lbase]);
    #pragma unroll
    for (int j = 0; j < NW; j++)
      gload16(Wb + woff[j], &Ws[bi][j * 2048 + lbase]);
  };

  // prologue: slabs 0,1 in flight; wait slab 0, barrier.
  stage(0, 0);
  if (KB > 1) stage(1, 1);
  __builtin_amdgcn_sched_barrier(0);
  if (KB > 1) asm volatile("s_waitcnt vmcnt(%0)" :: "n"(VC) : "memory");
  else        asm volatile("s_waitcnt vmcnt(0)" ::: "memory");
  __builtin_amdgcn_s_barrier();
  __builtin_amdgcn_sched_barrier(0);

  int cur = 0, nxt = 2;
  for (int kb = 0; kb < KB; kb++) {
    if (kb + 2 < KB) {
      stage(kb + 2, nxt);               // into (kb-1)%3: read finished last iter
      __builtin_amdgcn_sched_barrier(0);
    }
    bf16x8 af[MT][KS], bfr[NT][KS];
    #pragma unroll
    for (int mt = 0; mt < MT; mt++)
      #pragma unroll
      for (int st = 0; st < KS; st++)
        af[mt][st] = *(const bf16x8*)(&As[cur][0] + (wm + mt * 16 + l16) * BK +
                                      (((st * 4 + quad) ^ (l16 & MSK)) << 3));
    #pragma unroll
    for (int nt = 0; nt < NT; nt++)
      #pragma unroll
      for (int st = 0; st < KS; st++)
        bfr[nt][st] = *(const bf16x8*)(&Ws[cur][0] + (wn + nt * 16 + l16) * BK +
                                       (((st * 4 + quad) ^ (l16 & MSK)) << 3));
    #pragma unroll
    for (int st = 0; st < KS; st++)
      #pragma unroll
      for (int mt = 0; mt < MT; mt++)
        #pragma unroll
        for (int nt = 0; nt < NT; nt++)
          acc[mt][nt] = __builtin_amdgcn_mfma_f32_16x16x32_bf16(
              af[mt][st], bfr[nt][st], acc[mt][nt], 0, 0, 0);
    if (kb + 1 < KB) {
      __builtin_amdgcn_sched_barrier(0);
      // need slab kb+1 done; slab kb+2 (if issued) may stay in flight.
      if (kb + 2 < KB) asm volatile("s_waitcnt vmcnt(%0)" :: "n"(VC) : "memory");
      else             asm volatile("s_waitcnt vmcnt(0)" ::: "memory");
      __builtin_amdgcn_s_barrier();
      __builtin_amdgcn_sched_barrier(0);
      cur = (cur == 2) ? 0 : cur + 1;
      nxt = (nxt == 2) ? 0 : nxt + 1;
    }
  }

  #pragma unroll
  for (int mt = 0; mt < MT; mt++) {
    #pragma unroll
    for (int nt = 0; nt < NT; nt++) {
      int n = n0 + wn + nt * 16 + l16;
      if (n >= N) continue;
      #pragma unroll
      for (int r = 0; r < 4; r++) {
        int m = m0 + wm + mt * 16 + quad * 4 + r;
        float v = acc[mt][nt][r];
        if constexpr (EPI == EPI_F32_BIAS) {
          Cf[(size_t)m * ldc + n] = v + bias[n];
        } else if constexpr (EPI == EPI_BF16) {
          Cb[(size_t)m * ldc + n] = f2bf(v);
        } else if constexpr (EPI == EPI_F16_SOFTPLUS) {
          float tt = v + bias[n];
          float sp = (tt > 20.f) ? tt : log1pf(__expf(tt));
          ((unsigned short*)Cb)[(size_t)m * ldc + n] = f2h(sp);
        } else if constexpr (EPI == EPI_HALF_BF16) {
          Cb[(size_t)m * ldc + n] = f2bf(0.5f * v);
        } else if constexpr (EPI == EPI_GELU) {
          float tt = v + bias[n];
          Cb[(size_t)m * ldc + n] = f2bf(0.5f * tt * (1.f + erff(tt * 0.70710678118f)));
        } else if constexpr (EPI == EPI_PROJ) {
          int bb = m >> 9, d = m & 511;
          float tt = v + bias[n] + xlast[m];
          tt = tt * stdev[m] + means[m];
          Cf[((size_t)bb * PL_ + n) * DV_ + d] = tt;
        }
      }
    }
  }
}

// ---------------------------------------------------------------------------
extern "C" void kernel_launch(void* const* d_in, const int* in_sizes, int n_in,
                              void* d_out, int out_size, void* d_ws, size_t ws_size,
                              hipStream_t stream)
{
  (void)in_sizes; (void)n_in; (void)out_size; (void)ws_size;
  const float* x        = (const float*)d_in[0];
  const float* emb_w    = (const float*)d_in[1];
  const float* emb_b    = (const float*)d_in[2];
  const float* ln_g     = (const float*)d_in[3];
  const float* ln_b     = (const float*)d_in[4];
  const float* m_in_w   = (const float*)d_in[5];
  const float* m_conv_w = (const float*)d_in[6];
  const float* m_conv_b = (const float*)d_in[7];
  const float* m_xp_w   = (const float*)d_in[8];
  const float* m_dt_w   = (const float*)d_in[9];
  const float* m_dt_b   = (const float*)d_in[10];
  const float* m_A_log  = (const float*)d_in[11];
  const float* m_D      = (const float*)d_in[12];
  const float* m_out_w  = (const float*)d_in[13];
  const float* ffn_ln_g = (const float*)d_in[14];
  const float* ffn_ln_b = (const float*)d_in[15];
  const float* ffn_w1   = (const float*)d_in[16];
  const float* ffn_b1   = (const float*)d_in[17];
  const float* ffn_w2   = (const float*)d_in[18];
  const float* ffn_b2   = (const float*)d_in[19];
  const float* enc_g    = (const float*)d_in[20];
  const float* enc_b    = (const float*)d_in[21];
  const float* proj_w   = (const float*)d_in[22];
  const float* proj_b   = (const float*)d_in[23];
  float* out = (float*)d_out;

  char* ws = (char*)d_ws;
  const size_t MB = 1024 * 1024;
  float* h      = (float*)(ws + 0);        //  8 MB fp32 residual stream
  short* hn     = (short*)(ws + 8 * MB);   //  4 MB LN output bf16
  short* xz     = (short*)(ws + 12 * MB);  // 16 MB [M][2048] per-dir
  short* xc     = (short*)(ws + 28 * MB);  //  8 MB [M][1024] per-dir
  short* xdbl   = (short*)(ws + 36 * MB);  // .5 MB [M][64]
  float* stats  = (float*)(ws + 36 * MB + 512 * 1024);          // 64 KB
  unsigned short* dtb = (unsigned short*)(ws + 37 * MB); // 8 MB fp16 dt; scan_p3 dir1 writes y in place
  unsigned short* part_h = (unsigned short*)(ws + 45 * MB);     // 4 MB (scan only)
  unsigned short* part_A = (unsigned short*)(ws + 49 * MB);     // 4 MB (scan only)
  short* vtmp   = (short*)(ws + 47 * MB);  // 4 MB bf16 mamba out (after scans done)
  short* ftmp   = (short*)(ws + 47 * MB);  // 4 MB bf16 ffn2 out (aliases vtmp, sequential)
  short* yact0  = (short*)(ws + 53 * MB);  //  8 MB y(dir0); xnT aliases pre-layer
  short* xnT    = (short*)(ws + 53 * MB);
  float* means = stats, *stdevp = stats + 4096, *rstd = stats + 8192, *xlast = stats + 12288;

  // bf16 weight pool @ 61 MB (~32 MB total, high-water ~94 MB)
  short* emb_wb = (short*)(ws + 61 * MB);
  short* in_wb  = emb_wb + 262144;      // 6 x 2048x512
  short* xp_wb  = in_wb  + 6291456;     // 6 x 64x1024
  short* dt_wb  = xp_wb  + 393216;      // 6 x 1024x32
  short* out_wb = dt_wb  + 196608;      // 6 x 512x1024
  short* w1b    = out_wb + 3145728;     // 3 x 2048x512
  short* w2b    = w1b    + 3145728;     // 3 x 512x2048
  short* projb  = w2b    + 3145728;     // 96x512

  dim3 blk(256);
  const int NOSPLIT = 1 << 30;

  wcvt_k<<<dim3(16240), blk, 0, stream>>>(
      emb_w, m_in_w, m_xp_w, m_dt_w, m_out_w, ffn_w1, ffn_w2, proj_w,
      emb_wb, in_wb, xp_wb, dt_wb, out_wb, w1b, w2b, projb);

  stats_k<<<dim3(2, B_), blk, 0, stream>>>(x, means, stdevp, rstd, xlast);
  tnorm_k<<<dim3(8, 8, B_), blk, 0, stream>>>(x, means, rstd, xnT);
  // emb: M=4096, N=512, K=512 — 64x32 BK=64, grid (64, 16)
  gemm_k<EPI_F32_BIAS, 64, 32, 64><<<dim3(64, 16), blk, 0, stream>>>(
      xnT, xnT, emb_wb, emb_wb, NOSPLIT, DM_, L_, L_, L_,
      h, nullptr, DM_, emb_b, nullptr, nullptr, nullptr);

  for (int il = 0; il < EL_; il++) {
    if (il == 0)
      ln_k<0><<<dim3(4096), blk, 0, stream>>>(h, nullptr, nullptr, ln_g, ln_b, hn);
    else
      ln_k<2><<<dim3(4096), blk, 0, stream>>>(h, ftmp, ffn_b2 + (il - 1) * DM_,
          ln_g + il * DM_, ln_b + il * DM_, hn);
    for (int dir = 0; dir < 2; dir++) {
      int mod = 2 * il + dir;
      // in-proj: N=2048, K=512 — 64x128 BK=32, grid (64, 16) = 1024 blocks
      gemm_k<EPI_BF16, 64, 128, 32><<<dim3(64, 16), blk, 0, stream>>>(
          hn, hn, in_wb + (size_t)mod * 2 * DI_ * DM_,
          in_wb + (size_t)mod * 2 * DI_ * DM_, NOSPLIT, 2 * DI_, DM_, DM_, DM_,
          nullptr, xz, 2 * DI_, nullptr, nullptr, nullptr, nullptr);
      if (dir == 0)
        conv_k<0><<<dim3(16384), blk, 0, stream>>>(
            xz, m_conv_w + (size_t)mod * DI_ * DC_, m_conv_b + (size_t)mod * DI_, xc);
      else
        conv_k<1><<<dim3(16384), blk, 0, stream>>>(
            xz, m_conv_w + (size_t)mod * DI_ * DC_, m_conv_b + (size_t)mod * DI_, xc);
      // xdbl: N=64, K=1024 — 32x32 BK=64, grid (128, 2)
      gemm_k<EPI_BF16, 32, 32, 64><<<dim3(128, 2), blk, 0, stream>>>(
          xc, xc, xp_wb + (size_t)mod * (DTR_ + 2 * DS_) * DI_,
          xp_wb + (size_t)mod * (DTR_ + 2 * DS_) * DI_, NOSPLIT,
          DTR_ + 2 * DS_, DI_, DI_, DI_,
          nullptr, xdbl, DTR_ + 2 * DS_, nullptr, nullptr, nullptr, nullptr);
      // dt: N=1024, K=32 — 64x64 BK=32, grid (64, 16)
      gemm_k<EPI_F16_SOFTPLUS, 64, 64, 32><<<dim3(64, 16), blk, 0, stream>>>(
          xdbl, xdbl, dt_wb + (size_t)mod * DI_ * DTR_,
          dt_wb + (size_t)mod * DI_ * DTR_, NOSPLIT, DI_, DTR_, DTR_ + 2 * DS_, DTR_,
          nullptr, (short*)dtb, DI_, m_dt_b + (size_t)mod * DI_, nullptr, nullptr, nullptr);
      const float* Alog = m_A_log + (size_t)mod * DI_ * DS_;
      const float* Dp = m_D + (size_t)mod * DI_;
      short* ydst = (dir == 0) ? yact0 : (short*)dtb;   // dir1: in-place over dtb
      if (dir == 0) {
        scan_p1<0><<<dim3(128, CH_), blk, 0, stream>>>(dtb, xc, xdbl, Alog, part_h, part_A);
        scan_p2<<<dim3(512), blk, 0, stream>>>(part_h, part_A);
        scan_p3<0><<<dim3(128, CH_), blk, 0, stream>>>(dtb, xc, xdbl, xz, Alog, Dp, part_h, ydst);
      } else {
        scan_p1<1><<<dim3(128, CH_), blk, 0, stream>>>(dtb, xc, xdbl, Alog, part_h, part_A);
        scan_p2<<<dim3(512), blk, 0, stream>>>(part_h, part_A);
        scan_p3<1><<<dim3(128, CH_), blk, 0, stream>>>(dtb, xc, xdbl, xz, Alog, Dp, part_h, ydst);
      }
    }
    // out-proj (concat-K): vtmp = 0.5*(yf.Wf^T + yb.Wb^T) — 64x32 BK=64, grid (64,16)
    gemm_k<EPI_HALF_BF16, 64, 32, 64><<<dim3(64, 16), blk, 0, stream>>>(
        yact0, (const short*)dtb,
        out_wb + (size_t)(2 * il) * DM_ * DI_,
        out_wb + (size_t)(2 * il + 1) * DM_ * DI_,
        DI_, DM_, 2 * DI_, DI_, DI_,
        nullptr, vtmp, DM_, nullptr, nullptr, nullptr, nullptr);
    // fused: h += vtmp, then LN
    ln_k<1><<<dim3(4096), blk, 0, stream>>>(h, vtmp, nullptr,
        ffn_ln_g + il * DM_, ffn_ln_b + il * DM_, hn);
    // ffn1: N=2048, K=512 — 64x128 BK=32, grid (64, 16)
    gemm_k<EPI_GELU, 64, 128, 32><<<dim3(64, 16), blk, 0, stream>>>(
        hn, hn, w1b + (size_t)il * 4 * DM_ * DM_,
        w1b + (size_t)il * 4 * DM_ * DM_, NOSPLIT, 4 * DM_, DM_, DM_, DM_,
        nullptr, xz, 4 * DM_, ffn_b1 + (size_t)il * 4 * DM_, nullptr, nullptr, nullptr);
    // ffn2: N=512, K=2048 — 64x32 BK=64, grid (64, 16); streaming bf16 out
    gemm_k<EPI_BF16, 64, 32, 64><<<dim3(64, 16), blk, 0, stream>>>(
        xz, xz, w2b + (size_t)il * DM_ * 4 * DM_,
        w2b + (size_t)il * DM_ * 4 * DM_, NOSPLIT, DM_, 4 * DM_, 4 * DM_, 4 * DM_,
        nullptr, ftmp, DM_, nullptr, nullptr, nullptr, nullptr);
    // h += ftmp + ffn_b2 happens in the next layer's LN (or enc-LN below)
  }

  ln_k<2><<<dim3(4096), blk, 0, stream>>>(h, ftmp, ffn_b2 + 2 * DM_,
      enc_g, enc_b, hn);
  // proj: N=96, K=512 — 64x32 BK=64, grid (64, 3)
  gemm_k<EPI_PROJ, 64, 32, 64><<<dim3(64, 3), blk, 0, stream>>>(
      hn, hn, projb, projb, NOSPLIT, PL_, DM_, DM_, DM_,
      out, nullptr, 0, proj_b, xlast, stdevp, means);
}